// Round 9
// baseline (716.243 us; speedup 1.0000x reference)
//
#include <hip/hip_runtime.h>
#include <hip/hip_bf16.h>

// Problem constants (fixed by setup_inputs)
#define NN 8192
#define FF 512
#define HH 256
#define RR 16
#define BB 32
#define LL 256
#define CC 7
#define EE 262144
#define NBASE 30
#define DD 768

constexpr int FLAG_BIAS = 1, FLAG_RELU = 4, FLAG_TANH = 8,
              FLAG_SPLITOUT = 16, FLAG_TAILOUT = 32, FLAG_TAIL2 = 64;

typedef __attribute__((ext_vector_type(8))) short bf16x8;
typedef __attribute__((ext_vector_type(4))) float f32x4;

// ------------- dtype detection (robustness) -----------------------------------
__global__ __launch_bounds__(256) void detect_dtype(const unsigned short* __restrict__ xs,
                                                    int* __restrict__ flag) {
  __shared__ int red[256];
  int cnt = 0;
  for (int i = threadIdx.x * 2; i < 8192; i += 512) {
    unsigned short u = xs[i];
    int e = (u >> 7) & 0xFF;
    if (e >= 0xC0) cnt++;
  }
  red[threadIdx.x] = cnt;
  __syncthreads();
  for (int s = 128; s > 0; s >>= 1) {
    if (threadIdx.x < s) red[threadIdx.x] += red[threadIdx.x + s];
    __syncthreads();
  }
  if (threadIdx.x == 0) flag[0] = (red[0] > 16) ? 1 : 0;  // 1 = fp32 data
}

// ------------- unified prep: conversions + transposed splits, one launch -------
struct PSeg {
  const void* src;
  float* dst;
  __hip_bfloat16* hi;
  __hip_bfloat16* lo;
  __hip_bfloat16* hi2;   // optional second (strided) split dest (x -> em cols)
  __hip_bfloat16* lo2;
  long n;                // R*C elements
  int R, C, ld, off;     // transpose geometry (type==1)
  int type;              // 0 = linear, 1 = transpose-split
  int zero;
};
struct PTable {
  PSeg seg[16];
  int count;
  long total;
};

__global__ __launch_bounds__(256) void prep_all(PTable t, const int* __restrict__ flag) {
  const int fp32 = flag[0];
  for (long i = (long)blockIdx.x * 256 + threadIdx.x; i < t.total;
       i += (long)gridDim.x * 256) {
    long off = i;
    int s = 0;
    while (off >= t.seg[s].n) { off -= t.seg[s].n; s++; }
    const PSeg& sg = t.seg[s];
    if (sg.type == 0) {
      float v = 0.f;
      if (!sg.zero)
        v = fp32 ? ((const float*)sg.src)[off]
                 : __bfloat162float(((const __hip_bfloat16*)sg.src)[off]);
      if (sg.dst) sg.dst[off] = v;
      if (sg.hi) {
        __hip_bfloat16 h = __float2bfloat16(v);
        __hip_bfloat16 l = __float2bfloat16(v - __bfloat162float(h));
        sg.hi[off] = h;
        sg.lo[off] = l;
        if (sg.hi2) {  // x -> em cols 0:512 (row width 512 -> 768)
          long d2 = (off >> 9) * DD + (off & 511);
          sg.hi2[d2] = h;
          sg.lo2[d2] = l;
        }
      }
    } else {
      int r = (int)(off % sg.R), c = (int)(off / sg.R);
      float v = fp32 ? ((const float*)sg.src)[(long)r * sg.C + c]
                     : __bfloat162float(((const __hip_bfloat16*)sg.src)[(long)r * sg.C + c]);
      __hip_bfloat16 h = __float2bfloat16(v);
      long d = (long)c * sg.ld + sg.off + r;
      sg.hi[d] = h;
      sg.lo[d] = __float2bfloat16(v - __bfloat162float(h));
    }
  }
}

// ---- wt_nat[r][f][h] = sum_b comp[r,b]*basis[b][f][h] ------------------------
__global__ __launch_bounds__(256) void wt_gemm(
    const float* __restrict__ basis, const float* __restrict__ comp,
    float* __restrict__ wt_nat) {
  __shared__ float cs[RR * NBASE];
  int tid = threadIdx.x;
  for (int i = tid; i < RR * NBASE; i += 256) cs[i] = comp[i];
  __syncthreads();
  long col = (long)blockIdx.x * 256 + tid;
  float acc[RR] = {};
  for (int b = 0; b < NBASE; ++b) {
    float v = basis[(long)b * 131072 + col];
#pragma unroll
    for (int r = 0; r < RR; ++r) acc[r] += cs[r * NBASE + b] * v;
  }
#pragma unroll
  for (int r = 0; r < RR; ++r) wt_nat[(long)r * 131072 + col] = acc[r];
}

// ---- wt_nat [16][512][256] (r,f,h) -> wtc[(r*256+h)][512] hi/lo --------------
__global__ __launch_bounds__(256) void wt_transpose(
    const float* __restrict__ wt_nat,
    __hip_bfloat16* __restrict__ hi, __hip_bfloat16* __restrict__ lo) {
  __shared__ float t[32][33];
  const int r = blockIdx.z;
  const int f0 = blockIdx.y * 32, h0 = blockIdx.x * 32;
  const int c = threadIdx.x & 31, rw = threadIdx.x >> 5;
  const float* src = wt_nat + ((long)r * 512 + f0) * 256 + h0;
#pragma unroll
  for (int i = 0; i < 4; ++i)
    t[rw + i * 8][c] = src[(long)(rw + i * 8) * 256 + c];
  __syncthreads();
#pragma unroll
  for (int i = 0; i < 4; ++i) {
    int hh = rw + i * 8;
    float v = t[c][hh];
    long orow = (long)(r * 256 + h0 + hh) * 512 + f0 + c;
    __hip_bfloat16 hv = __float2bfloat16(v);
    hi[orow] = hv;
    lo[orow] = __float2bfloat16(v - __bfloat162float(hv));
  }
}

// ---------------- async global->LDS helper ------------------------------------
__device__ __forceinline__ void gload_lds16(const void* g, void* l) {
  __builtin_amdgcn_global_load_lds(
      (const __attribute__((address_space(1))) unsigned int*)g,
      (__attribute__((address_space(3))) unsigned int*)l, 16, 0, 0);
}

// ---------------- fused dual-precision MFMA GEMM (128x128, 2-phase) -----------
// Used for the small/batched GEMMs (out1, out2, scores, hidden).
__global__ __launch_bounds__(256, 3) void mfma_dual(
    const __hip_bfloat16* __restrict__ A, const __hip_bfloat16* __restrict__ Alo,
    const __hip_bfloat16* __restrict__ Bt, const __hip_bfloat16* __restrict__ Btlo,
    const float* __restrict__ bias, float* __restrict__ C, float* __restrict__ Ct,
    __hip_bfloat16* __restrict__ Chi, __hip_bfloat16* __restrict__ Clo,
    __hip_bfloat16* __restrict__ Chi2, __hip_bfloat16* __restrict__ Clo2,
    int K, int ldc, long sA, long sB, long sC, int flags) {
  __shared__ __hip_bfloat16 Ah[128 * 32];
  __shared__ __hip_bfloat16 Bh[128 * 32];
  __shared__ __hip_bfloat16 Al[128 * 32];
  __shared__ __hip_bfloat16 Bl[128 * 32];
  const int tid = threadIdx.x;
  const int w = tid >> 6, lane = tid & 63;
  const long z = blockIdx.z;
  const long row0 = (long)blockIdx.y * 128, col0 = (long)blockIdx.x * 128;
  const int wm = w & 1, wn = w >> 1;
  const int srow0 = (w * 128 + lane) >> 2;
  const int srow1 = (w * 128 + 64 + lane) >> 2;
  const int kch = (lane & 3) * 8;
  const int fr = lane & 15, q = lane >> 4;
  const bool hasAlo = (Alo != nullptr);
  const __hip_bfloat16* Az = A + z * sA;
  const __hip_bfloat16* Alz = hasAlo ? (Alo + z * sA) : nullptr;
  const __hip_bfloat16* Bz = Bt + z * sB;
  const __hip_bfloat16* Blz = Btlo + z * sB;
  const long aoff0 = (row0 + srow0) * K + kch, aoff1 = (row0 + srow1) * K + kch;
  const long boff0 = (col0 + srow0) * K + kch, boff1 = (col0 + srow1) * K + kch;
  f32x4 acc[4][4] = {};
  for (int k0 = 0; k0 < K; k0 += 32) {
    gload_lds16(Az + aoff0 + k0, Ah + w * 1024);
    gload_lds16(Az + aoff1 + k0, Ah + w * 1024 + 512);
    gload_lds16(Bz + boff0 + k0, Bh + w * 1024);
    gload_lds16(Bz + boff1 + k0, Bh + w * 1024 + 512);
    gload_lds16(Blz + boff0 + k0, Bl + w * 1024);
    gload_lds16(Blz + boff1 + k0, Bl + w * 1024 + 512);
    if (hasAlo) {
      gload_lds16(Alz + aoff0 + k0, Al + w * 1024);
      gload_lds16(Alz + aoff1 + k0, Al + w * 1024 + 512);
    }
    __syncthreads();
    bf16x8 ah[4], bh[4], bl[4];
#pragma unroll
    for (int i = 0; i < 4; ++i) {
      ah[i] = *(const bf16x8*)&Ah[(wm * 64 + i * 16 + fr) * 32 + q * 8];
      bh[i] = *(const bf16x8*)&Bh[(wn * 64 + i * 16 + fr) * 32 + q * 8];
      bl[i] = *(const bf16x8*)&Bl[(wn * 64 + i * 16 + fr) * 32 + q * 8];
    }
#pragma unroll
    for (int i = 0; i < 4; ++i)
#pragma unroll
      for (int j = 0; j < 4; ++j) {
        acc[i][j] = __builtin_amdgcn_mfma_f32_16x16x32_bf16(ah[i], bh[j], acc[i][j], 0, 0, 0);
        acc[i][j] = __builtin_amdgcn_mfma_f32_16x16x32_bf16(ah[i], bl[j], acc[i][j], 0, 0, 0);
      }
    if (hasAlo) {
      bf16x8 al[4];
#pragma unroll
      for (int i = 0; i < 4; ++i)
        al[i] = *(const bf16x8*)&Al[(wm * 64 + i * 16 + fr) * 32 + q * 8];
#pragma unroll
      for (int i = 0; i < 4; ++i)
#pragma unroll
        for (int j = 0; j < 4; ++j)
          acc[i][j] = __builtin_amdgcn_mfma_f32_16x16x32_bf16(al[i], bh[j], acc[i][j], 0, 0, 0);
    }
    __syncthreads();
  }
  const int cr = (lane >> 4) * 4, cc = lane & 15;
  float* Cz = C ? (C + z * sC) : nullptr;
  __hip_bfloat16* Chz = Chi ? (Chi + z * sC) : nullptr;
  __hip_bfloat16* Clz = Clo ? (Clo + z * sC) : nullptr;
#pragma unroll
  for (int i = 0; i < 4; ++i) {
    long rbase = row0 + wm * 64 + i * 16 + cr;
#pragma unroll
    for (int j = 0; j < 4; ++j) {
      long col = col0 + wn * 64 + j * 16 + cc;
      float bv = (flags & FLAG_BIAS) ? bias[col] : 0.f;
#pragma unroll
      for (int r = 0; r < 4; ++r) {
        float v = acc[i][j][r] + bv;
        if (flags & FLAG_RELU) v = fmaxf(v, 0.f);
        if (flags & FLAG_TANH) v = tanhf(v);
        long row = rbase + r;
        if ((flags & FLAG_TAIL2) && col >= 768) {
          long off2 = (row >> 8) * 65536 + (col - 768) * 256 + (row & 255);
          __hip_bfloat16 hv = __float2bfloat16(v);
          Chi2[off2] = hv;
          Clo2[off2] = __float2bfloat16(v - __bfloat162float(hv));
        } else if (flags & FLAG_SPLITOUT) {
          long off = row * ldc + col;
          __hip_bfloat16 hv = __float2bfloat16(v);
          Chz[off] = hv;
          Clz[off] = __float2bfloat16(v - __bfloat162float(hv));
        } else if ((flags & FLAG_TAILOUT) && col >= 4096) {
          Ct[row * 256 + (col - 4096)] = v;
        } else {
          Cz[row * ldc + col] = v;
        }
      }
    }
  }
}

// ---------------- 256x256 dual-precision MFMA GEMM (xw only) ------------------
// Measured r7: 104us, MfmaUtil 42%, WRITE exactly 128MiB (full-line stores).
// Grid 16x32 = 512 blocks = exactly 2 generations at 1 block/CU.
__device__ __forceinline__ void rd4(bf16x8 (&d)[4], const __hip_bfloat16* t,
                                    int rbase, int ro) {
#pragma unroll
  for (int i = 0; i < 4; ++i)
    d[i] = *(const bf16x8*)&t[(rbase + i * 16) * 32 + ro];
}

__device__ __forceinline__ void mm16(f32x4 (&acc)[8][4], int g,
                                     const bf16x8 (&a)[4], const bf16x8 (&b)[4]) {
#pragma unroll
  for (int i = 0; i < 4; ++i)
#pragma unroll
    for (int j = 0; j < 4; ++j)
      acc[g * 4 + i][j] =
          __builtin_amdgcn_mfma_f32_16x16x32_bf16(a[i], b[j], acc[g * 4 + i][j], 0, 0, 0);
}

__device__ __forceinline__ void mmq(f32x4 (&acc)[4][4],
                                    const bf16x8 (&a)[4], const bf16x8 (&b)[4]) {
#pragma unroll
  for (int i = 0; i < 4; ++i)
#pragma unroll
    for (int j = 0; j < 4; ++j)
      acc[i][j] =
          __builtin_amdgcn_mfma_f32_16x16x32_bf16(a[i], b[j], acc[i][j], 0, 0, 0);
}

__global__ __launch_bounds__(512, 2) void mfma_dual8(
    const __hip_bfloat16* __restrict__ A, const __hip_bfloat16* __restrict__ Alo,
    const __hip_bfloat16* __restrict__ Bt, const __hip_bfloat16* __restrict__ Btlo,
    const float* __restrict__ bias, float* __restrict__ C,
    int K, int ldc, int NT) {
  __shared__ __hip_bfloat16 sm[2][4][256 * 32];  // 128 KiB, [buf][Ah,Bh,Al,Bl]
  const int tid = threadIdx.x;
  const int w = tid >> 6, lane = tid & 63;
  const int wm = w >> 2, wn = w & 3;
  // T1: XCD-aware block swizzle (nwg = 512, % 8 == 0)
  const int nwg = gridDim.x * gridDim.y;
  const int bid = blockIdx.y * gridDim.x + blockIdx.x;
  const int swz = (bid & 7) * (nwg >> 3) + (bid >> 3);
  const int ty = swz % gridDim.y, tx = swz / gridDim.y;  // col-major: B-panel/XCD
  const long row0 = (long)ty * 256, col0 = (long)tx * 256;
  const int urow = tid >> 2;
  const int qg = (tid & 3) ^ ((tid >> 3) & 3);
  const long ga0 = (row0 + urow) * (long)K + qg * 8, ga1 = ga0 + 128L * K;
  const long gb0 = (col0 + urow) * (long)K + qg * 8, gb1 = gb0 + 128L * K;
  const int fr = lane & 15, q = lane >> 4;
  const int ro = fr * 32 + ((q ^ ((fr >> 1) & 3)) << 3);
  const int arow = wm * 128, brow = wn * 64;
  const int lw = w * 512;  // wave-uniform LDS chunk within a unit-half
  f32x4 acc[8][4] = {};

  auto stage = [&](int b, long k) {
    gload_lds16(A + ga0 + k, &sm[b][0][lw]);
    gload_lds16(A + ga1 + k, &sm[b][0][4096 + lw]);
    gload_lds16(Bt + gb0 + k, &sm[b][1][lw]);
    gload_lds16(Bt + gb1 + k, &sm[b][1][4096 + lw]);
    gload_lds16(Alo + ga0 + k, &sm[b][2][lw]);
    gload_lds16(Alo + ga1 + k, &sm[b][2][4096 + lw]);
    gload_lds16(Btlo + gb0 + k, &sm[b][3][lw]);
    gload_lds16(Btlo + gb1 + k, &sm[b][3][4096 + lw]);
  };

  // prologue: stage K-tile 0 into buf 0
  stage(0, 0);
  asm volatile("s_waitcnt vmcnt(0)" ::: "memory");
  __builtin_amdgcn_s_barrier();

  for (int t = 0; t < NT; ++t) {
    const int cur = t & 1, nxt = cur ^ 1;
    if (t + 1 < NT) stage(nxt, (long)(t + 1) << 5);
    const __hip_bfloat16* sA = sm[cur][0];
    const __hip_bfloat16* sB = sm[cur][1];
    const __hip_bfloat16* sAl = sm[cur][2];
    const __hip_bfloat16* sBl = sm[cur][3];
    bf16x8 bh[4], bl[4], a0[4], a1[4];
    rd4(bh, sB, brow, ro);
    rd4(bl, sBl, brow, ro);
    rd4(a0, sA, arow, ro);
    rd4(a1, sA, arow + 64, ro);
    __builtin_amdgcn_s_setprio(1);
    mm16(acc, 0, a0, bh);
    mm16(acc, 1, a1, bh);
    mm16(acc, 0, a0, bl);
    mm16(acc, 1, a1, bl);
    __builtin_amdgcn_s_setprio(0);
    rd4(a0, sAl, arow, ro);
    rd4(a1, sAl, arow + 64, ro);
    __builtin_amdgcn_s_setprio(1);
    mm16(acc, 0, a0, bh);
    mm16(acc, 1, a1, bh);
    __builtin_amdgcn_s_setprio(0);
    asm volatile("s_waitcnt vmcnt(0)" ::: "memory");
    __builtin_amdgcn_s_barrier();
  }

  // ---- epilogue: full-line stores via LDS slab transpose (write-allocate fix)
  float* ep = (float*)&sm[0][0][0];
  const int EPLD = 260;
  float bvj[4];
#pragma unroll
  for (int j = 0; j < 4; ++j) bvj[j] = bias[col0 + wn * 64 + j * 16 + fr];
  const int band = tid >> 8, tl = tid & 255;
#pragma unroll
  for (int i = 0; i < 8; ++i) {
    __builtin_amdgcn_s_barrier();  // LDS free (K-loop or previous slab done)
#pragma unroll
    for (int j = 0; j < 4; ++j) {
      int colt = wn * 64 + j * 16 + fr;
#pragma unroll
      for (int r = 0; r < 4; ++r)
        ep[(wm * 16 + q * 4 + r) * EPLD + colt] = acc[i][j][r] + bvj[j];
    }
    __builtin_amdgcn_s_barrier();
#pragma unroll
    for (int s = 0; s < 4; ++s) {
      int idx = s * 256 + tl;
      int rw = idx >> 6, c4 = idx & 63;
      float4 v = *(const float4*)&ep[(band * 16 + rw) * EPLD + c4 * 4];
      long grow = row0 + band * 128 + i * 16 + rw;
      *(float4*)&C[grow * (long)ldc + col0 + c4 * 4] = v;
    }
  }
}

// ---------------- 256x128 dual-precision MFMA GEMM (step-7 only) --------------
// Round-9: step-7 (M=8192,N=1024) on mfma_dual's 128^2 tile ran ~74us at
// ~22%-class MfmaUtil. 256x128 tile -> grid 8x32 = 256 blocks = EXACTLY 1
// generation at 1 block/CU, with the r7-proven dual8 inner structure (42%
// MfmaUtil class). 8 waves as 4Mx2N, per-wave 64x64, acc[4][4].
// LDS 96KiB: 2buf x {Ah(2u), Al(2u), Bh(1u), Bl(1u)} units of 128rows x 32K.
// Staging/read swizzles identical to dual8 (per-128-row-unit formulas).
// Epilogue: SPLITOUT (cols<768 -> Chi/Clo, ldc) / TAIL2 (cols>=768 -> emwT).
__global__ __launch_bounds__(512, 2) void mfma_step7(
    const __hip_bfloat16* __restrict__ A, const __hip_bfloat16* __restrict__ Alo,
    const __hip_bfloat16* __restrict__ Bt, const __hip_bfloat16* __restrict__ Btlo,
    const float* __restrict__ bias,
    __hip_bfloat16* __restrict__ Chi, __hip_bfloat16* __restrict__ Clo,
    __hip_bfloat16* __restrict__ Chi2, __hip_bfloat16* __restrict__ Clo2,
    int K, int ldc, int NT) {
  __shared__ __hip_bfloat16 sm[2][6][128 * 32];  // 96 KiB
  const int tid = threadIdx.x;
  const int w = tid >> 6, lane = tid & 63;
  const int wm = w >> 1, wn = w & 1;
  const int nwg = gridDim.x * gridDim.y;  // 256, %8==0
  const int bid = blockIdx.y * gridDim.x + blockIdx.x;
  const int swz = (bid & 7) * (nwg >> 3) + (bid >> 3);
  const int ty = swz % gridDim.y, tx = swz / gridDim.y;
  const long row0 = (long)ty * 256, col0 = (long)tx * 128;
  const int urow = tid >> 2;
  const int qg = (tid & 3) ^ ((tid >> 3) & 3);
  const long ga0 = (row0 + urow) * (long)K + qg * 8, ga1 = ga0 + 128L * K;
  const long gb0 = (col0 + urow) * (long)K + qg * 8;
  const int fr = lane & 15, q = lane >> 4;
  const int ro = fr * 32 + ((q ^ ((fr >> 1) & 3)) << 3);
  const int arow = wm * 64, brow = wn * 64;
  const int lw = w * 512;
  f32x4 acc[4][4] = {};

  auto stage = [&](int b, long k) {
    gload_lds16(A + ga0 + k, &sm[b][0][lw]);
    gload_lds16(A + ga1 + k, &sm[b][1][lw]);
    gload_lds16(Alo + ga0 + k, &sm[b][2][lw]);
    gload_lds16(Alo + ga1 + k, &sm[b][3][lw]);
    gload_lds16(Bt + gb0 + k, &sm[b][4][lw]);
    gload_lds16(Btlo + gb0 + k, &sm[b][5][lw]);
  };

  stage(0, 0);
  asm volatile("s_waitcnt vmcnt(0)" ::: "memory");
  __builtin_amdgcn_s_barrier();

  for (int t = 0; t < NT; ++t) {
    const int cur = t & 1, nxt = cur ^ 1;
    if (t + 1 < NT) stage(nxt, (long)(t + 1) << 5);
    const __hip_bfloat16* sA = &sm[cur][0][0];   // 256 rows (units 0-1)
    const __hip_bfloat16* sAl = &sm[cur][2][0];  // 256 rows (units 2-3)
    const __hip_bfloat16* sB = &sm[cur][4][0];   // 128 rows
    const __hip_bfloat16* sBl = &sm[cur][5][0];  // 128 rows
    bf16x8 ah[4], bh[4], bl[4];
    rd4(ah, sA, arow, ro);
    rd4(bh, sB, brow, ro);
    rd4(bl, sBl, brow, ro);
    __builtin_amdgcn_s_setprio(1);
    mmq(acc, ah, bh);
    mmq(acc, ah, bl);
    __builtin_amdgcn_s_setprio(0);
    rd4(ah, sAl, arow, ro);
    __builtin_amdgcn_s_setprio(1);
    mmq(acc, ah, bh);
    __builtin_amdgcn_s_setprio(0);
    asm volatile("s_waitcnt vmcnt(0)" ::: "memory");
    __builtin_amdgcn_s_barrier();
  }

  const int cr = q * 4;
#pragma unroll
  for (int i = 0; i < 4; ++i) {
    long rbase = row0 + wm * 64 + i * 16 + cr;
#pragma unroll
    for (int j = 0; j < 4; ++j) {
      long col = col0 + wn * 64 + j * 16 + fr;
      float bv = bias[col];
#pragma unroll
      for (int r = 0; r < 4; ++r) {
        float v = acc[i][j][r] + bv;
        long row = rbase + r;
        __hip_bfloat16 hv = __float2bfloat16(v);
        __hip_bfloat16 lv = __float2bfloat16(v - __bfloat162float(hv));
        if (col >= 768) {
          long off2 = (row >> 8) * 65536 + (col - 768) * 256 + (row & 255);
          Chi2[off2] = hv;
          Clo2[off2] = lv;
        } else {
          long off = row * (long)ldc + col;
          Chi[off] = hv;
          Clo[off] = lv;
        }
      }
    }
  }
}

// ---------------- edge kernels: CSR build + gathers ----------------------------
__global__ __launch_bounds__(256) void count_edges(
    const int* __restrict__ ei, const int* __restrict__ et, float* __restrict__ cnt) {
  int e = blockIdx.x * 256 + threadIdx.x;
  if (e < EE) atomicAdd(&cnt[ei[EE + e] * RR + et[e]], 1.0f);
}

__global__ __launch_bounds__(256) void scan_rowptr(
    const float* __restrict__ cntf, int* __restrict__ rowptr, int* __restrict__ fill) {
  __shared__ int part[256];
  int tid = threadIdx.x;
  int base = tid * 32;
  int local[32];
  int s = 0;
  for (int i = 0; i < 32; ++i) {
    local[i] = s;
    const float* c = &cntf[(base + i) * RR];
    int d = 0;
#pragma unroll
    for (int r = 0; r < RR; ++r) d += (int)c[r];
    s += d;
  }
  part[tid] = s;
  __syncthreads();
  for (int off = 1; off < 256; off <<= 1) {
    int v = (tid >= off) ? part[tid - off] : 0;
    __syncthreads();
    part[tid] += v;
    __syncthreads();
  }
  int prev = (tid == 0) ? 0 : part[tid - 1];
  for (int i = 0; i < 32; ++i) rowptr[base + i] = prev + local[i];
  if (tid == 255) rowptr[8192] = part[255];
  for (int i = tid; i < 8192; i += 256) fill[i] = 0;
}

__global__ __launch_bounds__(256) void edge_fill(
    const int* __restrict__ ei, const int* __restrict__ et,
    const int* __restrict__ rowptr, int* __restrict__ fill, int* __restrict__ eidx) {
  int e = blockIdx.x * 256 + threadIdx.x;
  if (e < EE) {
    int dst = ei[EE + e];
    int pos = rowptr[dst] + atomicAdd(&fill[dst], 1);
    eidx[pos] = ei[e] | (et[e] << 16);
  }
}

// out1 += mean-agg; emit split into a2o1 cols 256:512. Wave-split float4
// gather: wave w owns edges i%4==w, lane l covers cols 4l..4l+3.
__global__ __launch_bounds__(256) void rgcn_gather(
    const int* __restrict__ rowptr, const int* __restrict__ eidx,
    const float* __restrict__ cntf, const float* __restrict__ xw,
    float* __restrict__ out1, __hip_bfloat16* __restrict__ a2o1_hi,
    __hip_bfloat16* __restrict__ a2o1_lo) {
  const int dst = blockIdx.x;
  const int tid = threadIdx.x;
  const int w = tid >> 6, lane = tid & 63;
  const int c4 = lane * 4;
  __shared__ float inv[RR];
  __shared__ int se[256];
  __shared__ float part[3][256];
  if (tid < RR) inv[tid] = 1.0f / fmaxf(cntf[dst * RR + tid], 1.0f);
  const int beg = rowptr[dst], end = rowptr[dst + 1];
  float4 a = make_float4(0.f, 0.f, 0.f, 0.f);
  for (int c0 = beg; c0 < end; c0 += 256) {
    int n = min(256, end - c0);
    __syncthreads();
    if (tid < n) se[tid] = eidx[c0 + tid];
    __syncthreads();
    int i = w;
    for (; i + 4 < n; i += 8) {
      int p0 = se[i], p1 = se[i + 4];
      float4 v0 = *(const float4*)&xw[((long)(p0 & 0xFFFF) << 12) + ((p0 >> 16) << 8) + c4];
      float4 v1 = *(const float4*)&xw[((long)(p1 & 0xFFFF) << 12) + ((p1 >> 16) << 8) + c4];
      float s0 = inv[p0 >> 16], s1 = inv[p1 >> 16];
      a.x += v0.x * s0 + v1.x * s1;
      a.y += v0.y * s0 + v1.y * s1;
      a.z += v0.z * s0 + v1.z * s1;
      a.w += v0.w * s0 + v1.w * s1;
    }
    for (; i < n; i += 4) {
      int p0 = se[i];
      float4 v0 = *(const float4*)&xw[((long)(p0 & 0xFFFF) << 12) + ((p0 >> 16) << 8) + c4];
      float s0 = inv[p0 >> 16];
      a.x += v0.x * s0;
      a.y += v0.y * s0;
      a.z += v0.z * s0;
      a.w += v0.w * s0;
    }
  }
  __syncthreads();
  if (w) *(float4*)&part[w - 1][c4] = a;
  __syncthreads();
  if (w == 0) {
    float4 p0 = *(const float4*)&part[0][c4];
    float4 p1 = *(const float4*)&part[1][c4];
    float4 p2 = *(const float4*)&part[2][c4];
    long ob = ((long)dst << 8) + c4;
    float4 o = *(const float4*)&out1[ob];
    float t0 = o.x + a.x + p0.x + p1.x + p2.x;
    float t1 = o.y + a.y + p0.y + p1.y + p2.y;
    float t2 = o.z + a.z + p0.z + p1.z + p2.z;
    float t3 = o.w + a.w + p0.w + p1.w + p2.w;
    *(float4*)&out1[ob] = make_float4(t0, t1, t2, t3);
    __hip_bfloat16 h0 = __float2bfloat16(t0), h1 = __float2bfloat16(t1),
                   h2 = __float2bfloat16(t2), h3 = __float2bfloat16(t3);
    ushort4 hv = {*(unsigned short*)&h0, *(unsigned short*)&h1,
                  *(unsigned short*)&h2, *(unsigned short*)&h3};
    __hip_bfloat16 l0 = __float2bfloat16(t0 - __bfloat162float(h0)),
                   l1 = __float2bfloat16(t1 - __bfloat162float(h1)),
                   l2 = __float2bfloat16(t2 - __bfloat162float(h2)),
                   l3 = __float2bfloat16(t3 - __bfloat162float(h3));
    ushort4 lv = {*(unsigned short*)&l0, *(unsigned short*)&l1,
                  *(unsigned short*)&l2, *(unsigned short*)&l3};
    long d = (long)dst * 512 + 256 + c4;
    *(ushort4*)(a2o1_hi + d) = hv;
    *(ushort4*)(a2o1_lo + d) = lv;
  }
}

// a2o1 cols 0:256 = sum_{src->dst} out1[src] (wave-split float4, same scheme)
__global__ __launch_bounds__(256) void graphconv_gather(
    const int* __restrict__ rowptr, const int* __restrict__ eidx,
    const float* __restrict__ out1, __hip_bfloat16* __restrict__ a2o1_hi,
    __hip_bfloat16* __restrict__ a2o1_lo) {
  const int dst = blockIdx.x;
  const int tid = threadIdx.x;
  const int w = tid >> 6, lane = tid & 63;
  const int c4 = lane * 4;
  __shared__ int se[256];
  __shared__ float part[3][256];
  const int beg = rowptr[dst], end = rowptr[dst + 1];
  float4 a = make_float4(0.f, 0.f, 0.f, 0.f);
  for (int c0 = beg; c0 < end; c0 += 256) {
    int n = min(256, end - c0);
    __syncthreads();
    if (tid < n) se[tid] = eidx[c0 + tid];
    __syncthreads();
    int i = w;
    for (; i + 4 < n; i += 8) {
      float4 v0 = *(const float4*)&out1[((long)(se[i] & 0xFFFF) << 8) + c4];
      float4 v1 = *(const float4*)&out1[((long)(se[i + 4] & 0xFFFF) << 8) + c4];
      a.x += v0.x + v1.x;
      a.y += v0.y + v1.y;
      a.z += v0.z + v1.z;
      a.w += v0.w + v1.w;
    }
    for (; i < n; i += 4) {
      float4 v0 = *(const float4*)&out1[((long)(se[i] & 0xFFFF) << 8) + c4];
      a.x += v0.x;
      a.y += v0.y;
      a.z += v0.z;
      a.w += v0.w;
    }
  }
  __syncthreads();
  if (w) *(float4*)&part[w - 1][c4] = a;
  __syncthreads();
  if (w == 0) {
    float4 p0 = *(const float4*)&part[0][c4];
    float4 p1 = *(const float4*)&part[1][c4];
    float4 p2 = *(const float4*)&part[2][c4];
    float t0 = a.x + p0.x + p1.x + p2.x;
    float t1 = a.y + p0.y + p1.y + p2.y;
    float t2 = a.z + p0.z + p1.z + p2.z;
    float t3 = a.w + p0.w + p1.w + p2.w;
    __hip_bfloat16 h0 = __float2bfloat16(t0), h1 = __float2bfloat16(t1),
                   h2 = __float2bfloat16(t2), h3 = __float2bfloat16(t3);
    ushort4 hv = {*(unsigned short*)&h0, *(unsigned short*)&h1,
                  *(unsigned short*)&h2, *(unsigned short*)&h3};
    __hip_bfloat16 l0 = __float2bfloat16(t0 - __bfloat162float(h0)),
                   l1 = __float2bfloat16(t1 - __bfloat162float(h1)),
                   l2 = __float2bfloat16(t2 - __bfloat162float(h2)),
                   l3 = __float2bfloat16(t3 - __bfloat162float(h3));
    ushort4 lv = {*(unsigned short*)&l0, *(unsigned short*)&l1,
                  *(unsigned short*)&l2, *(unsigned short*)&l3};
    long d = (long)dst * 512 + c4;
    *(ushort4*)(a2o1_hi + d) = hv;
    *(ushort4*)(a2o1_lo + d) = lv;
  }
}

// ---------------- softmax over last dim (256), bf16 weights out ---------------
__global__ __launch_bounds__(256) void softmax256(const float* __restrict__ S,
                                                  __hip_bfloat16* __restrict__ Ab) {
  __shared__ float red[256];
  long row = blockIdx.x;
  const float* p = S + row * 256;
  int t = threadIdx.x;
  float v = p[t];
  red[t] = v;
  __syncthreads();
  for (int s = 128; s > 0; s >>= 1) {
    if (t < s) red[t] = fmaxf(red[t], red[t + s]);
    __syncthreads();
  }
  float m = red[0];
  __syncthreads();
  float e = __expf(v - m);
  red[t] = e;
  __syncthreads();
  for (int s = 128; s > 0; s >>= 1) {
    if (t < s) red[t] += red[t + s];
    __syncthreads();
  }
  Ab[row * 256 + t] = __float2bfloat16(e / red[0]);
}

// ---------------- logits + log_softmax over batch axis (faithful dim=1) -------
__global__ __launch_bounds__(256) void logits_lsm(
    const float* __restrict__ hidden, const float* __restrict__ w_fc,
    const float* __restrict__ b_fc, void* __restrict__ out_v,
    const int* __restrict__ flag) {
  __shared__ float wf[256 * 7];
  __shared__ float lg[224];
  __shared__ float corr[7];
  int t = blockIdx.x;
  int tid = threadIdx.x;
  for (int i = tid; i < 256 * 7; i += 256) wf[i] = w_fc[i];
  __syncthreads();
  if (tid < 224) {
    int b = tid / 7, c = tid % 7;
    const float* hr = hidden + ((long)((b << 8) + t) << 8);
    float s = b_fc[c];
    for (int k = 0; k < 256; ++k) s += hr[k] * wf[k * 7 + c];
    lg[tid] = s;
  }
  __syncthreads();
  if (tid < 7) {
    float m = -1e30f;
    for (int b = 0; b < BB; ++b) m = fmaxf(m, lg[b * 7 + tid]);
    float sum = 0.f;
    for (int b = 0; b < BB; ++b) sum += __expf(lg[b * 7 + tid] - m);
    corr[tid] = m + logf(sum);
  }
  __syncthreads();
  if (tid < 224) {
    float v = lg[tid] - corr[tid % 7];
    if (flag[0]) ((float*)out_v)[t * 224 + tid] = v;
    else ((__hip_bfloat16*)out_v)[t * 224 + tid] = __float2bfloat16(v);
  }
}

extern "C" void kernel_launch(void* const* d_in, const int* in_sizes, int n_in,
                              void* d_out, int out_size, void* d_ws, size_t ws_size,
                              hipStream_t stream) {
  const int* ei = (const int*)d_in[1];
  const int* et = (const int*)d_in[3];

  float* ws = (float*)d_ws;
  int* flag = (int*)d_ws;
  float* p = ws + 16;
  auto alloc = [&](long nf) { float* r = p; p += nf; return r; };
  float* w_fc_f = alloc(1792);
  float* b_rel_f = alloc(256);
  float* biasx = alloc(4352);                                    // [0..4095]=0, tail=bias1
  float* battx = alloc(1024);                                    // [0..767]=b_att, rest 0
  float* b_lin_f = alloc(256);
  float* b_fc_f = alloc(16);
  __hip_bfloat16* x_hi = (__hip_bfloat16*)alloc(2097152);        // [8192][512]
  __hip_bfloat16* x_lo = (__hip_bfloat16*)alloc(2097152);
  __hip_bfloat16* wae_hi = (__hip_bfloat16*)alloc(393216);       // [1024][768] = [w_att|w_lin]^T
  __hip_bfloat16* wae_lo = (__hip_bfloat16*)alloc(393216);
  __hip_bfloat16* wrr_hi = (__hip_bfloat16*)alloc(65536);        // [256][512] = [w_rel;w_root]^T
  __hip_bfloat16* wrr_lo = (__hip_bfloat16*)alloc(65536);
  __hip_bfloat16* wtc_hi = (__hip_bfloat16*)alloc(1114112);      // [4352][512]
  __hip_bfloat16* wtc_lo = (__hip_bfloat16*)alloc(1114112);
  float* basis_f = alloc(3932160);
  float* comp_f = alloc(512);
  float* xw = alloc(33554432);   // fp32 [8192][4096]; overlays below
  float* cnt = alloc(131072);
  float* out1 = alloc(2097152);
  __hip_bfloat16* a2o1_hi = (__hip_bfloat16*)alloc(2097152);     // [8192][512]
  __hip_bfloat16* a2o1_lo = (__hip_bfloat16*)alloc(2097152);
  float* hidden = alloc(2097152);
  int* rowptr = (int*)alloc(8208);
  int* fillc = (int*)alloc(8192);
  int* eidx = (int*)alloc(262144);
  // wt_nat overlays head of xw (consumed by wt_transpose before xw is written)
  float* wt_nat = xw;                                            // [16][512][256]
  // phase B overlays the (consumed) xw region
  float* em = xw;
  __hip_bfloat16* emwT_hi = (__hip_bfloat16*)(em + 2097152);     // [32][256][256]
  __hip_bfloat16* emwT_lo = (__hip_bfloat16*)(em + 3145728);
  __hip_bfloat16* em_hi = (__hip_bfloat16*)(em + 6291456);       // [8192][768]
  __hip_bfloat16* em_lo = (__hip_bfloat16*)(em + 9437184);
  __hip_bfloat16* X_hi = (__hip_bfloat16*)(em + 12582912);
  __hip_bfloat16* X_lo = (__hip_bfloat16*)(em + 15728640);
  float* scores = em + 18874368;                                 // 2,097,152 f
  __hip_bfloat16* a_b16 = (__hip_bfloat16*)(em + 20971520);      // 1,048,576 f

  // 0. dtype detect + one unified prep launch
  detect_dtype<<<1, 256, 0, stream>>>((const unsigned short*)d_in[0], flag);
  PTable T{};
  long tot = 0;
  int ns = 0;
  auto segL = [&](const void* s, float* d, __hip_bfloat16* hi, __hip_bfloat16* lo,
                  __hip_bfloat16* hi2, __hip_bfloat16* lo2, long n, int z) {
    T.seg[ns] = PSeg{s, d, hi, lo, hi2, lo2, n, 0, 0, 0, 0, 0, z};
    ns++; tot += n;
  };
  auto segT = [&](const void* s, __hip_bfloat16* hi, __hip_bfloat16* lo,
                  int R, int C, int ld, int off) {
    T.seg[ns] = PSeg{s, nullptr, hi, lo, nullptr, nullptr, (long)R * C, R, C, ld, off, 1, 0};
    ns++; tot += (long)R * C;
  };
  segL(d_in[0], nullptr, x_hi, x_lo, nullptr, nullptr, NN * FF, 0);
  segL(d_in[8], basis_f, nullptr, nullptr, nullptr, nullptr, NBASE * FF * HH, 0);
  segL(d_in[9], comp_f, nullptr, nullptr, nullptr, nullptr, RR * NBASE, 0);
  segL(d_in[13], b_rel_f, nullptr, nullptr, nullptr, nullptr, HH, 0);
  segL(d_in[16], battx, nullptr, nullptr, nullptr, nullptr, DD, 0);
  segL(nullptr, battx + DD, nullptr, nullptr, nullptr, nullptr, 256, 1);
  segL(d_in[18], b_lin_f, nullptr, nullptr, nullptr, nullptr, HH, 0);
  segL(d_in[19], w_fc_f, nullptr, nullptr, nullptr, nullptr, HH * CC, 0);
  segL(d_in[20], b_fc_f, nullptr, nullptr, nullptr, nullptr, CC, 0);
  segL(nullptr, biasx, nullptr, nullptr, nullptr, nullptr, 4096, 1);
  segL(d_in[11], biasx + 4096, nullptr, nullptr, nullptr, nullptr, HH, 0);
  segT(d_in[15], wae_hi, wae_lo, DD, DD, DD, 0);                 // w_att^T -> rows 0:768
  segT(d_in[17], wae_hi + 768 * 768, wae_lo + 768 * 768, DD, HH, DD, 0);  // w_lin^T -> rows 768:1024
  segT(d_in[10], wtc_hi + 4096 * 512, wtc_lo + 4096 * 512, FF, HH, FF, 0);  // root1^T
  segT(d_in[12], wrr_hi, wrr_lo, HH, HH, 512, 0);                // w_rel^T
  segT(d_in[14], wrr_hi, wrr_lo, HH, HH, 512, 256);              // w_root^T
  T.count = ns;
  T.total = tot;
  prep_all<<<4096, 256, 0, stream>>>(T, flag);

  // 1. Wt: coalesced GEMM into natural layout, then LDS-tiled transpose + split
  wt_gemm<<<131072 / 256, 256, 0, stream>>>(basis_f, comp_f, wt_nat);
  wt_transpose<<<dim3(8, 16, 16), 256, 0, stream>>>(wt_nat, wtc_hi, wtc_lo);
  // 2. xw = x @ W (cols 0:4096): grid 16x32 = 512 blocks = exactly 2
  //    generations at 1 block/CU.
  mfma_dual8<<<dim3(16, 32), 512, 0, stream>>>(
      x_hi, x_lo, wtc_hi, wtc_lo, biasx, xw, FF, 4096, FF / 32);
  // 2b. out1 = x @ root1 + bias1 (the former TAILOUT columns), small 2-phase GEMM
  mfma_dual<<<dim3(2, 64, 1), 256, 0, stream>>>(
      x_hi, x_lo, wtc_hi + 4096 * 512, wtc_lo + 4096 * 512, biasx + 4096,
      out1, nullptr, nullptr, nullptr, nullptr, nullptr, FF, HH, 0, 0, 0, FLAG_BIAS);
  // 3. CSR build
  hipMemsetAsync(cnt, 0, 131072 * sizeof(float), stream);
  count_edges<<<EE / 256, 256, 0, stream>>>(ei, et, cnt);
  scan_rowptr<<<1, 256, 0, stream>>>(cnt, rowptr, fillc);
  edge_fill<<<EE / 256, 256, 0, stream>>>(ei, et, rowptr, fillc, eidx);
  // 4/5. aggregations (gather); emit [agg2|out1] hi/lo as out2-GEMM A operand
  rgcn_gather<<<NN, 256, 0, stream>>>(rowptr, eidx, cnt, xw, out1, a2o1_hi, a2o1_lo);
  graphconv_gather<<<NN, 256, 0, stream>>>(rowptr, eidx, out1, a2o1_hi, a2o1_lo);
  // 6. em cols 0:512 = x (split, from x_hi/x_lo after xw is dead)
  extern __global__ void copy_xsplit_k(const __hip_bfloat16*, const __hip_bfloat16*,
                                       __hip_bfloat16*, __hip_bfloat16*);
  copy_xsplit_k<<<(NN * FF) / 256, 256, 0, stream>>>(x_hi, x_lo, em_hi, em_lo);
  // 6b. out2 -> em cols 512:768 via split-MFMA
  mfma_dual<<<dim3(2, 64, 1), 256, 0, stream>>>(
      a2o1_hi, a2o1_lo, wrr_hi, wrr_lo, b_rel_f, nullptr, nullptr,
      em_hi + 512, em_lo + 512, nullptr, nullptr, 512, DD, 0, 0, 0,
      FLAG_BIAS | FLAG_SPLITOUT);
  // 7. [X | emwT] = em @ [w_att | w_lin] (+b_att|0); cols>=768 -> transposed split
  //    256x128 tile: grid 8x32 = 256 blocks = exactly 1 generation.
  mfma_step7<<<dim3(8, 32), 512, 0, stream>>>(
      em_hi, em_lo, wae_hi, wae_lo, battx, X_hi, X_lo, emwT_hi, emwT_lo,
      DD, DD / 32 * 32 == DD ? DD : DD, DD / 32);
  // 8. scores = tanh(X_b . em_b^T) (batched, fp32 out)
  mfma_dual<<<dim3(2, 2, BB), 256, 0, stream>>>(
      X_hi, X_lo, em_hi, em_lo, nullptr, scores, nullptr, nullptr, nullptr,
      nullptr, nullptr, DD, LL, (long)LL * DD, (long)LL * DD, (long)LL * LL, FLAG_TANH);
  // 9. softmax over s -> bf16 attention weights
  softmax256<<<BB * LL, 256, 0, stream>>>(scores, a_b16);
  // 10. hidden = relu(a @ emwT + b_lin)
  mfma_dual<<<dim3(2, 2, BB), 256, 0, stream>>>(
      a_b16, nullptr, emwT_hi, emwT_lo, b_lin_f, hidden, nullptr, nullptr, nullptr,
      nullptr, nullptr, LL, HH, (long)LL * LL, (long)LL * HH, (long)LL * HH,
      FLAG_BIAS | FLAG_RELU);
  // 11. logits + log_softmax over batch axis
  logits_lsm<<<LL, 256, 0, stream>>>(hidden, w_fc_f, b_fc_f, d_out, flag);
}

// copy x_hi/x_lo [8192][512] into em_hi/lo [8192][768] cols 0:512
__global__ __launch_bounds__(256) void copy_xsplit_k(
    const __hip_bfloat16* __restrict__ xh, const __hip_bfloat16* __restrict__ xl,
    __hip_bfloat16* __restrict__ eh, __hip_bfloat16* __restrict__ el) {
  int idx = blockIdx.x * 256 + threadIdx.x;  // 8192*512
  int n = idx >> 9, f = idx & 511;
  long d = (long)n * DD + f;
  eh[d] = xh[idx];
  el[d] = xl[idx];
}

// Round 10
// 622.661 us; speedup vs baseline: 1.1503x; 1.1503x over previous
//
#include <hip/hip_runtime.h>
#include <hip/hip_bf16.h>

// Problem constants (fixed by setup_inputs)
#define NN 8192
#define FF 512
#define HH 256
#define RR 16
#define BB 32
#define LL 256
#define CC 7
#define EE 262144
#define NBASE 30
#define DD 768

constexpr int FLAG_BIAS = 1, FLAG_RELU = 4, FLAG_TANH = 8,
              FLAG_SPLITOUT = 16, FLAG_TAILOUT = 32, FLAG_TAIL2 = 64;

typedef __attribute__((ext_vector_type(8))) short bf16x8;
typedef __attribute__((ext_vector_type(4))) float f32x4;

// ------------- dtype detection (robustness) -----------------------------------
__global__ __launch_bounds__(256) void detect_dtype(const unsigned short* __restrict__ xs,
                                                    int* __restrict__ flag) {
  __shared__ int red[256];
  int cnt = 0;
  for (int i = threadIdx.x * 2; i < 8192; i += 512) {
    unsigned short u = xs[i];
    int e = (u >> 7) & 0xFF;
    if (e >= 0xC0) cnt++;
  }
  red[threadIdx.x] = cnt;
  __syncthreads();
  for (int s = 128; s > 0; s >>= 1) {
    if (threadIdx.x < s) red[threadIdx.x] += red[threadIdx.x + s];
    __syncthreads();
  }
  if (threadIdx.x == 0) flag[0] = (red[0] > 16) ? 1 : 0;  // 1 = fp32 data
}

// ------------- unified prep: conversions + transposed splits, one launch -------
struct PSeg {
  const void* src;
  float* dst;
  __hip_bfloat16* hi;
  __hip_bfloat16* lo;
  __hip_bfloat16* hi2;   // optional second (strided) split dest (x -> em cols)
  __hip_bfloat16* lo2;
  long n;                // R*C elements
  int R, C, ld, off;     // transpose geometry (type==1)
  int type;              // 0 = linear, 1 = transpose-split
  int zero;
};
struct PTable {
  PSeg seg[16];
  int count;
  long total;
};

__global__ __launch_bounds__(256) void prep_all(PTable t, const int* __restrict__ flag) {
  const int fp32 = flag[0];
  for (long i = (long)blockIdx.x * 256 + threadIdx.x; i < t.total;
       i += (long)gridDim.x * 256) {
    long off = i;
    int s = 0;
    while (off >= t.seg[s].n) { off -= t.seg[s].n; s++; }
    const PSeg& sg = t.seg[s];
    if (sg.type == 0) {
      float v = 0.f;
      if (!sg.zero)
        v = fp32 ? ((const float*)sg.src)[off]
                 : __bfloat162float(((const __hip_bfloat16*)sg.src)[off]);
      if (sg.dst) sg.dst[off] = v;
      if (sg.hi) {
        __hip_bfloat16 h = __float2bfloat16(v);
        __hip_bfloat16 l = __float2bfloat16(v - __bfloat162float(h));
        sg.hi[off] = h;
        sg.lo[off] = l;
        if (sg.hi2) {  // x -> em cols 0:512 (row width 512 -> 768)
          long d2 = (off >> 9) * DD + (off & 511);
          sg.hi2[d2] = h;
          sg.lo2[d2] = l;
        }
      }
    } else {
      int r = (int)(off % sg.R), c = (int)(off / sg.R);
      float v = fp32 ? ((const float*)sg.src)[(long)r * sg.C + c]
                     : __bfloat162float(((const __hip_bfloat16*)sg.src)[(long)r * sg.C + c]);
      __hip_bfloat16 h = __float2bfloat16(v);
      long d = (long)c * sg.ld + sg.off + r;
      sg.hi[d] = h;
      sg.lo[d] = __float2bfloat16(v - __bfloat162float(h));
    }
  }
}

// ---- wt_nat[r][f][h] = sum_b comp[r,b]*basis[b][f][h] ------------------------
__global__ __launch_bounds__(256) void wt_gemm(
    const float* __restrict__ basis, const float* __restrict__ comp,
    float* __restrict__ wt_nat) {
  __shared__ float cs[RR * NBASE];
  int tid = threadIdx.x;
  for (int i = tid; i < RR * NBASE; i += 256) cs[i] = comp[i];
  __syncthreads();
  long col = (long)blockIdx.x * 256 + tid;
  float acc[RR] = {};
  for (int b = 0; b < NBASE; ++b) {
    float v = basis[(long)b * 131072 + col];
#pragma unroll
    for (int r = 0; r < RR; ++r) acc[r] += cs[r * NBASE + b] * v;
  }
#pragma unroll
  for (int r = 0; r < RR; ++r) wt_nat[(long)r * 131072 + col] = acc[r];
}

// ---- wt_nat [16][512][256] (r,f,h) -> wtc[(r*256+h)][512] hi/lo --------------
__global__ __launch_bounds__(256) void wt_transpose(
    const float* __restrict__ wt_nat,
    __hip_bfloat16* __restrict__ hi, __hip_bfloat16* __restrict__ lo) {
  __shared__ float t[32][33];
  const int r = blockIdx.z;
  const int f0 = blockIdx.y * 32, h0 = blockIdx.x * 32;
  const int c = threadIdx.x & 31, rw = threadIdx.x >> 5;
  const float* src = wt_nat + ((long)r * 512 + f0) * 256 + h0;
#pragma unroll
  for (int i = 0; i < 4; ++i)
    t[rw + i * 8][c] = src[(long)(rw + i * 8) * 256 + c];
  __syncthreads();
#pragma unroll
  for (int i = 0; i < 4; ++i) {
    int hh = rw + i * 8;
    float v = t[c][hh];
    long orow = (long)(r * 256 + h0 + hh) * 512 + f0 + c;
    __hip_bfloat16 hv = __float2bfloat16(v);
    hi[orow] = hv;
    lo[orow] = __float2bfloat16(v - __bfloat162float(hv));
  }
}

// ---------------- async global->LDS helper ------------------------------------
__device__ __forceinline__ void gload_lds16(const void* g, void* l) {
  __builtin_amdgcn_global_load_lds(
      (const __attribute__((address_space(1))) unsigned int*)g,
      (__attribute__((address_space(3))) unsigned int*)l, 16, 0, 0);
}

// ---------------- fused dual-precision MFMA GEMM (128x128, 2-phase) -----------
// Used for all GEMMs except the big xw GEMM. At 3 blocks/CU its staging is
// TLP-hidden — beats 1-block/CU exact-fit structures for K-heavy small-N
// shapes (r9 lesson: mfma_step7 256x128 @1/CU regressed vs this @3/CU).
__global__ __launch_bounds__(256, 3) void mfma_dual(
    const __hip_bfloat16* __restrict__ A, const __hip_bfloat16* __restrict__ Alo,
    const __hip_bfloat16* __restrict__ Bt, const __hip_bfloat16* __restrict__ Btlo,
    const float* __restrict__ bias, float* __restrict__ C, float* __restrict__ Ct,
    __hip_bfloat16* __restrict__ Chi, __hip_bfloat16* __restrict__ Clo,
    __hip_bfloat16* __restrict__ Chi2, __hip_bfloat16* __restrict__ Clo2,
    int K, int ldc, long sA, long sB, long sC, int flags) {
  __shared__ __hip_bfloat16 Ah[128 * 32];
  __shared__ __hip_bfloat16 Bh[128 * 32];
  __shared__ __hip_bfloat16 Al[128 * 32];
  __shared__ __hip_bfloat16 Bl[128 * 32];
  const int tid = threadIdx.x;
  const int w = tid >> 6, lane = tid & 63;
  const long z = blockIdx.z;
  const long row0 = (long)blockIdx.y * 128, col0 = (long)blockIdx.x * 128;
  const int wm = w & 1, wn = w >> 1;
  const int srow0 = (w * 128 + lane) >> 2;
  const int srow1 = (w * 128 + 64 + lane) >> 2;
  const int kch = (lane & 3) * 8;
  const int fr = lane & 15, q = lane >> 4;
  const bool hasAlo = (Alo != nullptr);
  const __hip_bfloat16* Az = A + z * sA;
  const __hip_bfloat16* Alz = hasAlo ? (Alo + z * sA) : nullptr;
  const __hip_bfloat16* Bz = Bt + z * sB;
  const __hip_bfloat16* Blz = Btlo + z * sB;
  const long aoff0 = (row0 + srow0) * K + kch, aoff1 = (row0 + srow1) * K + kch;
  const long boff0 = (col0 + srow0) * K + kch, boff1 = (col0 + srow1) * K + kch;
  f32x4 acc[4][4] = {};
  for (int k0 = 0; k0 < K; k0 += 32) {
    gload_lds16(Az + aoff0 + k0, Ah + w * 1024);
    gload_lds16(Az + aoff1 + k0, Ah + w * 1024 + 512);
    gload_lds16(Bz + boff0 + k0, Bh + w * 1024);
    gload_lds16(Bz + boff1 + k0, Bh + w * 1024 + 512);
    gload_lds16(Blz + boff0 + k0, Bl + w * 1024);
    gload_lds16(Blz + boff1 + k0, Bl + w * 1024 + 512);
    if (hasAlo) {
      gload_lds16(Alz + aoff0 + k0, Al + w * 1024);
      gload_lds16(Alz + aoff1 + k0, Al + w * 1024 + 512);
    }
    __syncthreads();
    bf16x8 ah[4], bh[4], bl[4];
#pragma unroll
    for (int i = 0; i < 4; ++i) {
      ah[i] = *(const bf16x8*)&Ah[(wm * 64 + i * 16 + fr) * 32 + q * 8];
      bh[i] = *(const bf16x8*)&Bh[(wn * 64 + i * 16 + fr) * 32 + q * 8];
      bl[i] = *(const bf16x8*)&Bl[(wn * 64 + i * 16 + fr) * 32 + q * 8];
    }
#pragma unroll
    for (int i = 0; i < 4; ++i)
#pragma unroll
      for (int j = 0; j < 4; ++j) {
        acc[i][j] = __builtin_amdgcn_mfma_f32_16x16x32_bf16(ah[i], bh[j], acc[i][j], 0, 0, 0);
        acc[i][j] = __builtin_amdgcn_mfma_f32_16x16x32_bf16(ah[i], bl[j], acc[i][j], 0, 0, 0);
      }
    if (hasAlo) {
      bf16x8 al[4];
#pragma unroll
      for (int i = 0; i < 4; ++i)
        al[i] = *(const bf16x8*)&Al[(wm * 64 + i * 16 + fr) * 32 + q * 8];
#pragma unroll
      for (int i = 0; i < 4; ++i)
#pragma unroll
        for (int j = 0; j < 4; ++j)
          acc[i][j] = __builtin_amdgcn_mfma_f32_16x16x32_bf16(al[i], bh[j], acc[i][j], 0, 0, 0);
    }
    __syncthreads();
  }
  const int cr = (lane >> 4) * 4, cc = lane & 15;
  float* Cz = C ? (C + z * sC) : nullptr;
  __hip_bfloat16* Chz = Chi ? (Chi + z * sC) : nullptr;
  __hip_bfloat16* Clz = Clo ? (Clo + z * sC) : nullptr;
#pragma unroll
  for (int i = 0; i < 4; ++i) {
    long rbase = row0 + wm * 64 + i * 16 + cr;
#pragma unroll
    for (int j = 0; j < 4; ++j) {
      long col = col0 + wn * 64 + j * 16 + cc;
      float bv = (flags & FLAG_BIAS) ? bias[col] : 0.f;
#pragma unroll
      for (int r = 0; r < 4; ++r) {
        float v = acc[i][j][r] + bv;
        if (flags & FLAG_RELU) v = fmaxf(v, 0.f);
        if (flags & FLAG_TANH) v = tanhf(v);
        long row = rbase + r;
        if ((flags & FLAG_TAIL2) && col >= 768) {
          long off2 = (row >> 8) * 65536 + (col - 768) * 256 + (row & 255);
          __hip_bfloat16 hv = __float2bfloat16(v);
          Chi2[off2] = hv;
          Clo2[off2] = __float2bfloat16(v - __bfloat162float(hv));
        } else if (flags & FLAG_SPLITOUT) {
          long off = row * ldc + col;
          __hip_bfloat16 hv = __float2bfloat16(v);
          Chz[off] = hv;
          Clz[off] = __float2bfloat16(v - __bfloat162float(hv));
        } else if ((flags & FLAG_TAILOUT) && col >= 4096) {
          Ct[row * 256 + (col - 4096)] = v;
        } else {
          Cz[row * ldc + col] = v;
        }
      }
    }
  }
}

// ---------------- 256x256 dual-precision MFMA GEMM (xw only) ------------------
// Measured r7/r8: ~104us, MfmaUtil 42%, WRITE exactly 128MiB (full-line stores).
// Grid 16x32 = 512 blocks = exactly 2 generations at 1 block/CU.
__device__ __forceinline__ void rd4(bf16x8 (&d)[4], const __hip_bfloat16* t,
                                    int rbase, int ro) {
#pragma unroll
  for (int i = 0; i < 4; ++i)
    d[i] = *(const bf16x8*)&t[(rbase + i * 16) * 32 + ro];
}

__device__ __forceinline__ void mm16(f32x4 (&acc)[8][4], int g,
                                     const bf16x8 (&a)[4], const bf16x8 (&b)[4]) {
#pragma unroll
  for (int i = 0; i < 4; ++i)
#pragma unroll
    for (int j = 0; j < 4; ++j)
      acc[g * 4 + i][j] =
          __builtin_amdgcn_mfma_f32_16x16x32_bf16(a[i], b[j], acc[g * 4 + i][j], 0, 0, 0);
}

__global__ __launch_bounds__(512, 2) void mfma_dual8(
    const __hip_bfloat16* __restrict__ A, const __hip_bfloat16* __restrict__ Alo,
    const __hip_bfloat16* __restrict__ Bt, const __hip_bfloat16* __restrict__ Btlo,
    const float* __restrict__ bias, float* __restrict__ C,
    int K, int ldc, int NT) {
  __shared__ __hip_bfloat16 sm[2][4][256 * 32];  // 128 KiB, [buf][Ah,Bh,Al,Bl]
  const int tid = threadIdx.x;
  const int w = tid >> 6, lane = tid & 63;
  const int wm = w >> 2, wn = w & 3;
  // T1: XCD-aware block swizzle (nwg = 512, % 8 == 0)
  const int nwg = gridDim.x * gridDim.y;
  const int bid = blockIdx.y * gridDim.x + blockIdx.x;
  const int swz = (bid & 7) * (nwg >> 3) + (bid >> 3);
  const int ty = swz % gridDim.y, tx = swz / gridDim.y;  // col-major: B-panel/XCD
  const long row0 = (long)ty * 256, col0 = (long)tx * 256;
  const int urow = tid >> 2;
  const int qg = (tid & 3) ^ ((tid >> 3) & 3);
  const long ga0 = (row0 + urow) * (long)K + qg * 8, ga1 = ga0 + 128L * K;
  const long gb0 = (col0 + urow) * (long)K + qg * 8, gb1 = gb0 + 128L * K;
  const int fr = lane & 15, q = lane >> 4;
  const int ro = fr * 32 + ((q ^ ((fr >> 1) & 3)) << 3);
  const int arow = wm * 128, brow = wn * 64;
  const int lw = w * 512;  // wave-uniform LDS chunk within a unit-half
  f32x4 acc[8][4] = {};

  auto stage = [&](int b, long k) {
    gload_lds16(A + ga0 + k, &sm[b][0][lw]);
    gload_lds16(A + ga1 + k, &sm[b][0][4096 + lw]);
    gload_lds16(Bt + gb0 + k, &sm[b][1][lw]);
    gload_lds16(Bt + gb1 + k, &sm[b][1][4096 + lw]);
    gload_lds16(Alo + ga0 + k, &sm[b][2][lw]);
    gload_lds16(Alo + ga1 + k, &sm[b][2][4096 + lw]);
    gload_lds16(Btlo + gb0 + k, &sm[b][3][lw]);
    gload_lds16(Btlo + gb1 + k, &sm[b][3][4096 + lw]);
  };

  // prologue: stage K-tile 0 into buf 0
  stage(0, 0);
  asm volatile("s_waitcnt vmcnt(0)" ::: "memory");
  __builtin_amdgcn_s_barrier();

  for (int t = 0; t < NT; ++t) {
    const int cur = t & 1, nxt = cur ^ 1;
    if (t + 1 < NT) stage(nxt, (long)(t + 1) << 5);
    const __hip_bfloat16* sA = sm[cur][0];
    const __hip_bfloat16* sB = sm[cur][1];
    const __hip_bfloat16* sAl = sm[cur][2];
    const __hip_bfloat16* sBl = sm[cur][3];
    bf16x8 bh[4], bl[4], a0[4], a1[4];
    rd4(bh, sB, brow, ro);
    rd4(bl, sBl, brow, ro);
    rd4(a0, sA, arow, ro);
    rd4(a1, sA, arow + 64, ro);
    __builtin_amdgcn_s_setprio(1);
    mm16(acc, 0, a0, bh);
    mm16(acc, 1, a1, bh);
    mm16(acc, 0, a0, bl);
    mm16(acc, 1, a1, bl);
    __builtin_amdgcn_s_setprio(0);
    rd4(a0, sAl, arow, ro);
    rd4(a1, sAl, arow + 64, ro);
    __builtin_amdgcn_s_setprio(1);
    mm16(acc, 0, a0, bh);
    mm16(acc, 1, a1, bh);
    __builtin_amdgcn_s_setprio(0);
    asm volatile("s_waitcnt vmcnt(0)" ::: "memory");
    __builtin_amdgcn_s_barrier();
  }

  // ---- epilogue: full-line stores via LDS slab transpose (write-allocate fix)
  float* ep = (float*)&sm[0][0][0];
  const int EPLD = 260;
  float bvj[4];
#pragma unroll
  for (int j = 0; j < 4; ++j) bvj[j] = bias[col0 + wn * 64 + j * 16 + fr];
  const int band = tid >> 8, tl = tid & 255;
#pragma unroll
  for (int i = 0; i < 8; ++i) {
    __builtin_amdgcn_s_barrier();  // LDS free (K-loop or previous slab done)
#pragma unroll
    for (int j = 0; j < 4; ++j) {
      int colt = wn * 64 + j * 16 + fr;
#pragma unroll
      for (int r = 0; r < 4; ++r)
        ep[(wm * 16 + q * 4 + r) * EPLD + colt] = acc[i][j][r] + bvj[j];
    }
    __builtin_amdgcn_s_barrier();
#pragma unroll
    for (int s = 0; s < 4; ++s) {
      int idx = s * 256 + tl;
      int rw = idx >> 6, c4 = idx & 63;
      float4 v = *(const float4*)&ep[(band * 16 + rw) * EPLD + c4 * 4];
      long grow = row0 + band * 128 + i * 16 + rw;
      *(float4*)&C[grow * (long)ldc + col0 + c4 * 4] = v;
    }
  }
}

// ---------------- edge kernels: CSR build + gathers ----------------------------
__global__ __launch_bounds__(256) void count_edges(
    const int* __restrict__ ei, const int* __restrict__ et, float* __restrict__ cnt) {
  int e = blockIdx.x * 256 + threadIdx.x;
  if (e < EE) atomicAdd(&cnt[ei[EE + e] * RR + et[e]], 1.0f);
}

__global__ __launch_bounds__(256) void scan_rowptr(
    const float* __restrict__ cntf, int* __restrict__ rowptr, int* __restrict__ fill) {
  __shared__ int part[256];
  int tid = threadIdx.x;
  int base = tid * 32;
  int local[32];
  int s = 0;
  for (int i = 0; i < 32; ++i) {
    local[i] = s;
    const float* c = &cntf[(base + i) * RR];
    int d = 0;
#pragma unroll
    for (int r = 0; r < RR; ++r) d += (int)c[r];
    s += d;
  }
  part[tid] = s;
  __syncthreads();
  for (int off = 1; off < 256; off <<= 1) {
    int v = (tid >= off) ? part[tid - off] : 0;
    __syncthreads();
    part[tid] += v;
    __syncthreads();
  }
  int prev = (tid == 0) ? 0 : part[tid - 1];
  for (int i = 0; i < 32; ++i) rowptr[base + i] = prev + local[i];
  if (tid == 255) rowptr[8192] = part[255];
  for (int i = tid; i < 8192; i += 256) fill[i] = 0;
}

__global__ __launch_bounds__(256) void edge_fill(
    const int* __restrict__ ei, const int* __restrict__ et,
    const int* __restrict__ rowptr, int* __restrict__ fill, int* __restrict__ eidx) {
  int e = blockIdx.x * 256 + threadIdx.x;
  if (e < EE) {
    int dst = ei[EE + e];
    int pos = rowptr[dst] + atomicAdd(&fill[dst], 1);
    eidx[pos] = ei[e] | (et[e] << 16);
  }
}

// out1 += mean-agg; emit split into a2o1 cols 256:512. Wave-split float4
// gather: wave w owns edges i%4==w, lane l covers cols 4l..4l+3.
__global__ __launch_bounds__(256) void rgcn_gather(
    const int* __restrict__ rowptr, const int* __restrict__ eidx,
    const float* __restrict__ cntf, const float* __restrict__ xw,
    float* __restrict__ out1, __hip_bfloat16* __restrict__ a2o1_hi,
    __hip_bfloat16* __restrict__ a2o1_lo) {
  const int dst = blockIdx.x;
  const int tid = threadIdx.x;
  const int w = tid >> 6, lane = tid & 63;
  const int c4 = lane * 4;
  __shared__ float inv[RR];
  __shared__ int se[256];
  __shared__ float part[3][256];
  if (tid < RR) inv[tid] = 1.0f / fmaxf(cntf[dst * RR + tid], 1.0f);
  const int beg = rowptr[dst], end = rowptr[dst + 1];
  float4 a = make_float4(0.f, 0.f, 0.f, 0.f);
  for (int c0 = beg; c0 < end; c0 += 256) {
    int n = min(256, end - c0);
    __syncthreads();
    if (tid < n) se[tid] = eidx[c0 + tid];
    __syncthreads();
    int i = w;
    for (; i + 4 < n; i += 8) {
      int p0 = se[i], p1 = se[i + 4];
      float4 v0 = *(const float4*)&xw[((long)(p0 & 0xFFFF) << 12) + ((p0 >> 16) << 8) + c4];
      float4 v1 = *(const float4*)&xw[((long)(p1 & 0xFFFF) << 12) + ((p1 >> 16) << 8) + c4];
      float s0 = inv[p0 >> 16], s1 = inv[p1 >> 16];
      a.x += v0.x * s0 + v1.x * s1;
      a.y += v0.y * s0 + v1.y * s1;
      a.z += v0.z * s0 + v1.z * s1;
      a.w += v0.w * s0 + v1.w * s1;
    }
    for (; i < n; i += 4) {
      int p0 = se[i];
      float4 v0 = *(const float4*)&xw[((long)(p0 & 0xFFFF) << 12) + ((p0 >> 16) << 8) + c4];
      float s0 = inv[p0 >> 16];
      a.x += v0.x * s0;
      a.y += v0.y * s0;
      a.z += v0.z * s0;
      a.w += v0.w * s0;
    }
  }
  __syncthreads();
  if (w) *(float4*)&part[w - 1][c4] = a;
  __syncthreads();
  if (w == 0) {
    float4 p0 = *(const float4*)&part[0][c4];
    float4 p1 = *(const float4*)&part[1][c4];
    float4 p2 = *(const float4*)&part[2][c4];
    long ob = ((long)dst << 8) + c4;
    float4 o = *(const float4*)&out1[ob];
    float t0 = o.x + a.x + p0.x + p1.x + p2.x;
    float t1 = o.y + a.y + p0.y + p1.y + p2.y;
    float t2 = o.z + a.z + p0.z + p1.z + p2.z;
    float t3 = o.w + a.w + p0.w + p1.w + p2.w;
    *(float4*)&out1[ob] = make_float4(t0, t1, t2, t3);
    __hip_bfloat16 h0 = __float2bfloat16(t0), h1 = __float2bfloat16(t1),
                   h2 = __float2bfloat16(t2), h3 = __float2bfloat16(t3);
    ushort4 hv = {*(unsigned short*)&h0, *(unsigned short*)&h1,
                  *(unsigned short*)&h2, *(unsigned short*)&h3};
    __hip_bfloat16 l0 = __float2bfloat16(t0 - __bfloat162float(h0)),
                   l1 = __float2bfloat16(t1 - __bfloat162float(h1)),
                   l2 = __float2bfloat16(t2 - __bfloat162float(h2)),
                   l3 = __float2bfloat16(t3 - __bfloat162float(h3));
    ushort4 lv = {*(unsigned short*)&l0, *(unsigned short*)&l1,
                  *(unsigned short*)&l2, *(unsigned short*)&l3};
    long d = (long)dst * 512 + 256 + c4;
    *(ushort4*)(a2o1_hi + d) = hv;
    *(ushort4*)(a2o1_lo + d) = lv;
  }
}

// a2o1 cols 0:256 = sum_{src->dst} out1[src] (wave-split float4, same scheme)
__global__ __launch_bounds__(256) void graphconv_gather(
    const int* __restrict__ rowptr, const int* __restrict__ eidx,
    const float* __restrict__ out1, __hip_bfloat16* __restrict__ a2o1_hi,
    __hip_bfloat16* __restrict__ a2o1_lo) {
  const int dst = blockIdx.x;
  const int tid = threadIdx.x;
  const int w = tid >> 6, lane = tid & 63;
  const int c4 = lane * 4;
  __shared__ int se[256];
  __shared__ float part[3][256];
  const int beg = rowptr[dst], end = rowptr[dst + 1];
  float4 a = make_float4(0.f, 0.f, 0.f, 0.f);
  for (int c0 = beg; c0 < end; c0 += 256) {
    int n = min(256, end - c0);
    __syncthreads();
    if (tid < n) se[tid] = eidx[c0 + tid];
    __syncthreads();
    int i = w;
    for (; i + 4 < n; i += 8) {
      float4 v0 = *(const float4*)&out1[((long)(se[i] & 0xFFFF) << 8) + c4];
      float4 v1 = *(const float4*)&out1[((long)(se[i + 4] & 0xFFFF) << 8) + c4];
      a.x += v0.x + v1.x;
      a.y += v0.y + v1.y;
      a.z += v0.z + v1.z;
      a.w += v0.w + v1.w;
    }
    for (; i < n; i += 4) {
      float4 v0 = *(const float4*)&out1[((long)(se[i] & 0xFFFF) << 8) + c4];
      a.x += v0.x;
      a.y += v0.y;
      a.z += v0.z;
      a.w += v0.w;
    }
  }
  __syncthreads();
  if (w) *(float4*)&part[w - 1][c4] = a;
  __syncthreads();
  if (w == 0) {
    float4 p0 = *(const float4*)&part[0][c4];
    float4 p1 = *(const float4*)&part[1][c4];
    float4 p2 = *(const float4*)&part[2][c4];
    float t0 = a.x + p0.x + p1.x + p2.x;
    float t1 = a.y + p0.y + p1.y + p2.y;
    float t2 = a.z + p0.z + p1.z + p2.z;
    float t3 = a.w + p0.w + p1.w + p2.w;
    __hip_bfloat16 h0 = __float2bfloat16(t0), h1 = __float2bfloat16(t1),
                   h2 = __float2bfloat16(t2), h3 = __float2bfloat16(t3);
    ushort4 hv = {*(unsigned short*)&h0, *(unsigned short*)&h1,
                  *(unsigned short*)&h2, *(unsigned short*)&h3};
    __hip_bfloat16 l0 = __float2bfloat16(t0 - __bfloat162float(h0)),
                   l1 = __float2bfloat16(t1 - __bfloat162float(h1)),
                   l2 = __float2bfloat16(t2 - __bfloat162float(h2)),
                   l3 = __float2bfloat16(t3 - __bfloat162float(h3));
    ushort4 lv = {*(unsigned short*)&l0, *(unsigned short*)&l1,
                  *(unsigned short*)&l2, *(unsigned short*)&l3};
    long d = (long)dst * 512 + c4;
    *(ushort4*)(a2o1_hi + d) = hv;
    *(ushort4*)(a2o1_lo + d) = lv;
  }
}

// ---------------- softmax over last dim (256), bf16 weights out ---------------
__global__ __launch_bounds__(256) void softmax256(const float* __restrict__ S,
                                                  __hip_bfloat16* __restrict__ Ab) {
  __shared__ float red[256];
  long row = blockIdx.x;
  const float* p = S + row * 256;
  int t = threadIdx.x;
  float v = p[t];
  red[t] = v;
  __syncthreads();
  for (int s = 128; s > 0; s >>= 1) {
    if (t < s) red[t] = fmaxf(red[t], red[t + s]);
    __syncthreads();
  }
  float m = red[0];
  __syncthreads();
  float e = __expf(v - m);
  red[t] = e;
  __syncthreads();
  for (int s = 128; s > 0; s >>= 1) {
    if (t < s) red[t] += red[t + s];
    __syncthreads();
  }
  Ab[row * 256 + t] = __float2bfloat16(e / red[0]);
}

// ---------------- logits + log_softmax over batch axis (faithful dim=1) -------
__global__ __launch_bounds__(256) void logits_lsm(
    const float* __restrict__ hidden, const float* __restrict__ w_fc,
    const float* __restrict__ b_fc, void* __restrict__ out_v,
    const int* __restrict__ flag) {
  __shared__ float wf[256 * 7];
  __shared__ float lg[224];
  __shared__ float corr[7];
  int t = blockIdx.x;
  int tid = threadIdx.x;
  for (int i = tid; i < 256 * 7; i += 256) wf[i] = w_fc[i];
  __syncthreads();
  if (tid < 224) {
    int b = tid / 7, c = tid % 7;
    const float* hr = hidden + ((long)((b << 8) + t) << 8);
    float s = b_fc[c];
    for (int k = 0; k < 256; ++k) s += hr[k] * wf[k * 7 + c];
    lg[tid] = s;
  }
  __syncthreads();
  if (tid < 7) {
    float m = -1e30f;
    for (int b = 0; b < BB; ++b) m = fmaxf(m, lg[b * 7 + tid]);
    float sum = 0.f;
    for (int b = 0; b < BB; ++b) sum += __expf(lg[b * 7 + tid] - m);
    corr[tid] = m + logf(sum);
  }
  __syncthreads();
  if (tid < 224) {
    float v = lg[tid] - corr[tid % 7];
    if (flag[0]) ((float*)out_v)[t * 224 + tid] = v;
    else ((__hip_bfloat16*)out_v)[t * 224 + tid] = __float2bfloat16(v);
  }
}

extern "C" void kernel_launch(void* const* d_in, const int* in_sizes, int n_in,
                              void* d_out, int out_size, void* d_ws, size_t ws_size,
                              hipStream_t stream) {
  const int* ei = (const int*)d_in[1];
  const int* et = (const int*)d_in[3];

  float* ws = (float*)d_ws;
  int* flag = (int*)d_ws;
  float* p = ws + 16;
  auto alloc = [&](long nf) { float* r = p; p += nf; return r; };
  float* w_fc_f = alloc(1792);
  float* b_rel_f = alloc(256);
  float* biasx = alloc(4352);                                    // [0..4095]=0, tail=bias1
  float* battx = alloc(1024);                                    // [0..767]=b_att, rest 0
  float* b_lin_f = alloc(256);
  float* b_fc_f = alloc(16);
  __hip_bfloat16* x_hi = (__hip_bfloat16*)alloc(2097152);        // [8192][512]
  __hip_bfloat16* x_lo = (__hip_bfloat16*)alloc(2097152);
  __hip_bfloat16* wae_hi = (__hip_bfloat16*)alloc(393216);       // [1024][768] = [w_att|w_lin]^T
  __hip_bfloat16* wae_lo = (__hip_bfloat16*)alloc(393216);
  __hip_bfloat16* wrr_hi = (__hip_bfloat16*)alloc(65536);        // [256][512] = [w_rel;w_root]^T
  __hip_bfloat16* wrr_lo = (__hip_bfloat16*)alloc(65536);
  __hip_bfloat16* wtc_hi = (__hip_bfloat16*)alloc(1114112);      // [4352][512]
  __hip_bfloat16* wtc_lo = (__hip_bfloat16*)alloc(1114112);
  float* basis_f = alloc(3932160);
  float* comp_f = alloc(512);
  float* xw = alloc(33554432);   // fp32 [8192][4096]; overlays below
  float* cnt = alloc(131072);
  float* out1 = alloc(2097152);
  __hip_bfloat16* a2o1_hi = (__hip_bfloat16*)alloc(2097152);     // [8192][512]
  __hip_bfloat16* a2o1_lo = (__hip_bfloat16*)alloc(2097152);
  float* hidden = alloc(2097152);
  int* rowptr = (int*)alloc(8208);
  int* fillc = (int*)alloc(8192);
  int* eidx = (int*)alloc(262144);
  // wt_nat overlays head of xw (consumed by wt_transpose before xw is written)
  float* wt_nat = xw;                                            // [16][512][256]
  // phase B overlays the (consumed) xw region
  float* em = xw;
  __hip_bfloat16* emwT_hi = (__hip_bfloat16*)(em + 2097152);     // [32][256][256]
  __hip_bfloat16* emwT_lo = (__hip_bfloat16*)(em + 3145728);
  __hip_bfloat16* em_hi = (__hip_bfloat16*)(em + 6291456);       // [8192][768]
  __hip_bfloat16* em_lo = (__hip_bfloat16*)(em + 9437184);
  __hip_bfloat16* X_hi = (__hip_bfloat16*)(em + 12582912);
  __hip_bfloat16* X_lo = (__hip_bfloat16*)(em + 15728640);
  float* scores = em + 18874368;                                 // 2,097,152 f
  __hip_bfloat16* a_b16 = (__hip_bfloat16*)(em + 20971520);      // 1,048,576 f

  // 0. dtype detect + one unified prep launch
  detect_dtype<<<1, 256, 0, stream>>>((const unsigned short*)d_in[0], flag);
  PTable T{};
  long tot = 0;
  int ns = 0;
  auto segL = [&](const void* s, float* d, __hip_bfloat16* hi, __hip_bfloat16* lo,
                  __hip_bfloat16* hi2, __hip_bfloat16* lo2, long n, int z) {
    T.seg[ns] = PSeg{s, d, hi, lo, hi2, lo2, n, 0, 0, 0, 0, 0, z};
    ns++; tot += n;
  };
  auto segT = [&](const void* s, __hip_bfloat16* hi, __hip_bfloat16* lo,
                  int R, int C, int ld, int off) {
    T.seg[ns] = PSeg{s, nullptr, hi, lo, nullptr, nullptr, (long)R * C, R, C, ld, off, 1, 0};
    ns++; tot += (long)R * C;
  };
  segL(d_in[0], nullptr, x_hi, x_lo, nullptr, nullptr, NN * FF, 0);
  segL(d_in[8], basis_f, nullptr, nullptr, nullptr, nullptr, NBASE * FF * HH, 0);
  segL(d_in[9], comp_f, nullptr, nullptr, nullptr, nullptr, RR * NBASE, 0);
  segL(d_in[13], b_rel_f, nullptr, nullptr, nullptr, nullptr, HH, 0);
  segL(d_in[16], battx, nullptr, nullptr, nullptr, nullptr, DD, 0);
  segL(nullptr, battx + DD, nullptr, nullptr, nullptr, nullptr, 256, 1);
  segL(d_in[18], b_lin_f, nullptr, nullptr, nullptr, nullptr, HH, 0);
  segL(d_in[19], w_fc_f, nullptr, nullptr, nullptr, nullptr, HH * CC, 0);
  segL(d_in[20], b_fc_f, nullptr, nullptr, nullptr, nullptr, CC, 0);
  segL(nullptr, biasx, nullptr, nullptr, nullptr, nullptr, 4096, 1);
  segL(d_in[11], biasx + 4096, nullptr, nullptr, nullptr, nullptr, HH, 0);
  segT(d_in[15], wae_hi, wae_lo, DD, DD, DD, 0);                 // w_att^T -> rows 0:768
  segT(d_in[17], wae_hi + 768 * 768, wae_lo + 768 * 768, DD, HH, DD, 0);  // w_lin^T -> rows 768:1024
  segT(d_in[10], wtc_hi + 4096 * 512, wtc_lo + 4096 * 512, FF, HH, FF, 0);  // root1^T
  segT(d_in[12], wrr_hi, wrr_lo, HH, HH, 512, 0);                // w_rel^T
  segT(d_in[14], wrr_hi, wrr_lo, HH, HH, 512, 256);              // w_root^T
  T.count = ns;
  T.total = tot;
  prep_all<<<4096, 256, 0, stream>>>(T, flag);

  // 1. Wt: coalesced GEMM into natural layout, then LDS-tiled transpose + split
  wt_gemm<<<131072 / 256, 256, 0, stream>>>(basis_f, comp_f, wt_nat);
  wt_transpose<<<dim3(8, 16, 16), 256, 0, stream>>>(wt_nat, wtc_hi, wtc_lo);
  // 2. xw = x @ W (cols 0:4096): grid 16x32 = 512 blocks = exactly 2
  //    generations at 1 block/CU.
  mfma_dual8<<<dim3(16, 32), 512, 0, stream>>>(
      x_hi, x_lo, wtc_hi, wtc_lo, biasx, xw, FF, 4096, FF / 32);
  // 2b. out1 = x @ root1 + bias1 (the former TAILOUT columns), small 2-phase GEMM
  mfma_dual<<<dim3(2, 64, 1), 256, 0, stream>>>(
      x_hi, x_lo, wtc_hi + 4096 * 512, wtc_lo + 4096 * 512, biasx + 4096,
      out1, nullptr, nullptr, nullptr, nullptr, nullptr, FF, HH, 0, 0, 0, FLAG_BIAS);
  // 3. CSR build
  hipMemsetAsync(cnt, 0, 131072 * sizeof(float), stream);
  count_edges<<<EE / 256, 256, 0, stream>>>(ei, et, cnt);
  scan_rowptr<<<1, 256, 0, stream>>>(cnt, rowptr, fillc);
  edge_fill<<<EE / 256, 256, 0, stream>>>(ei, et, rowptr, fillc, eidx);
  // 4/5. aggregations (gather); emit [agg2|out1] hi/lo as out2-GEMM A operand
  rgcn_gather<<<NN, 256, 0, stream>>>(rowptr, eidx, cnt, xw, out1, a2o1_hi, a2o1_lo);
  graphconv_gather<<<NN, 256, 0, stream>>>(rowptr, eidx, out1, a2o1_hi, a2o1_lo);
  // 6. em cols 0:512 = x (split, from x_hi/x_lo after xw is dead)
  extern __global__ void copy_xsplit_k(const __hip_bfloat16*, const __hip_bfloat16*,
                                       __hip_bfloat16*, __hip_bfloat16*);
  copy_xsplit_k<<<(NN * FF) / 256, 256, 0, stream>>>(x_hi, x_lo, em_hi, em_lo);
  // 6b. out2 -> em cols 512:768 via split-MFMA
  mfma_dual<<<dim3(2, 64, 1), 256, 0, stream>>>(
      a2o1_hi, a2o1_lo, wrr_hi, wrr_lo, b_rel_f, nullptr, nullptr,
      em_hi + 512, em_lo + 512, nullptr, nullptr, 512, DD, 0, 0, 0,
      FLAG_BIAS | FLAG_SPLITOUT);
  // 7. [X | emwT] = em @ [w_att | w_lin] (+b_att|0); cols>=768 -> transposed split
  //    2-phase mfma_dual @ 3 blocks/CU (r9: 1-block/CU 256x128 variant regressed).
  mfma_dual<<<dim3(8, 64, 1), 256, 0, stream>>>(
      em_hi, em_lo, wae_hi, wae_lo, battx, nullptr, nullptr, X_hi, X_lo,
      emwT_hi, emwT_lo, DD, DD, 0, 0, 0, FLAG_BIAS | FLAG_SPLITOUT | FLAG_TAIL2);
  // 8. scores = tanh(X_b . em_b^T) (batched, fp32 out)
  mfma_dual<<<dim3(2, 2, BB), 256, 0, stream>>>(
      X_hi, X_lo, em_hi, em_lo, nullptr, scores, nullptr, nullptr, nullptr,
      nullptr, nullptr, DD, LL, (long)LL * DD, (long)LL * DD, (long)LL * LL, FLAG_TANH);
  // 9. softmax over s -> bf16 attention weights
  softmax256<<<BB * LL, 256, 0, stream>>>(scores, a_b16);
  // 10. hidden = relu(a @ emwT + b_lin)
  mfma_dual<<<dim3(2, 2, BB), 256, 0, stream>>>(
      a_b16, nullptr, emwT_hi, emwT_lo, b_lin_f, hidden, nullptr, nullptr, nullptr,
      nullptr, nullptr, LL, HH, (long)LL * LL, (long)LL * HH, (long)LL * HH,
      FLAG_BIAS | FLAG_RELU);
  // 11. logits + log_softmax over batch axis
  logits_lsm<<<LL, 256, 0, stream>>>(hidden, w_fc_f, b_fc_f, d_out, flag);
}

// copy x_hi/x_lo [8192][512] into em_hi/lo [8192][768] cols 0:512
__global__ __launch_bounds__(256) void copy_xsplit_k(
    const __hip_bfloat16* __restrict__ xh, const __hip_bfloat16* __restrict__ xl,
    __hip_bfloat16* __restrict__ eh, __hip_bfloat16* __restrict__ el) {
  int idx = blockIdx.x * 256 + threadIdx.x;  // 8192*512
  int n = idx >> 9, f = idx & 511;
  long d = (long)n * DD + f;
  eh[d] = xh[idx];
  el[d] = xl[idx];
}

// Round 11
// 619.533 us; speedup vs baseline: 1.1561x; 1.0050x over previous
//
#include <hip/hip_runtime.h>
#include <hip/hip_bf16.h>

// Problem constants (fixed by setup_inputs)
#define NN 8192
#define FF 512
#define HH 256
#define RR 16
#define BB 32
#define LL 256
#define CC 7
#define EE 262144
#define NBASE 30
#define DD 768

constexpr int FLAG_BIAS = 1, FLAG_RELU = 4, FLAG_TANH = 8,
              FLAG_SPLITOUT = 16, FLAG_TAILOUT = 32, FLAG_TAIL2 = 64;

typedef __attribute__((ext_vector_type(8))) short bf16x8;
typedef __attribute__((ext_vector_type(4))) float f32x4;

// ------------- dtype detection (robustness) -----------------------------------
__global__ __launch_bounds__(256) void detect_dtype(const unsigned short* __restrict__ xs,
                                                    int* __restrict__ flag) {
  __shared__ int red[256];
  int cnt = 0;
  for (int i = threadIdx.x * 2; i < 8192; i += 512) {
    unsigned short u = xs[i];
    int e = (u >> 7) & 0xFF;
    if (e >= 0xC0) cnt++;
  }
  red[threadIdx.x] = cnt;
  __syncthreads();
  for (int s = 128; s > 0; s >>= 1) {
    if (threadIdx.x < s) red[threadIdx.x] += red[threadIdx.x + s];
    __syncthreads();
  }
  if (threadIdx.x == 0) flag[0] = (red[0] > 16) ? 1 : 0;  // 1 = fp32 data
}

// ------------- unified prep: conversions + transposed splits, one launch -------
struct PSeg {
  const void* src;
  float* dst;
  __hip_bfloat16* hi;
  __hip_bfloat16* lo;
  __hip_bfloat16* hi2;   // optional second (strided) split dest (x -> em cols)
  __hip_bfloat16* lo2;
  long n;                // R*C elements
  int R, C, ld, off;     // transpose geometry (type==1)
  int type;              // 0 = linear, 1 = transpose-split
  int zero;
};
struct PTable {
  PSeg seg[16];
  int count;
  long total;
};

__global__ __launch_bounds__(256) void prep_all(PTable t, const int* __restrict__ flag) {
  const int fp32 = flag[0];
  for (long i = (long)blockIdx.x * 256 + threadIdx.x; i < t.total;
       i += (long)gridDim.x * 256) {
    long off = i;
    int s = 0;
    while (off >= t.seg[s].n) { off -= t.seg[s].n; s++; }
    const PSeg& sg = t.seg[s];
    if (sg.type == 0) {
      float v = 0.f;
      if (!sg.zero)
        v = fp32 ? ((const float*)sg.src)[off]
                 : __bfloat162float(((const __hip_bfloat16*)sg.src)[off]);
      if (sg.dst) sg.dst[off] = v;
      if (sg.hi) {
        __hip_bfloat16 h = __float2bfloat16(v);
        __hip_bfloat16 l = __float2bfloat16(v - __bfloat162float(h));
        sg.hi[off] = h;
        sg.lo[off] = l;
        if (sg.hi2) {  // x -> em cols 0:512 (row width 512 -> 768)
          long d2 = (off >> 9) * DD + (off & 511);
          sg.hi2[d2] = h;
          sg.lo2[d2] = l;
        }
      }
    } else {
      int r = (int)(off % sg.R), c = (int)(off / sg.R);
      float v = fp32 ? ((const float*)sg.src)[(long)r * sg.C + c]
                     : __bfloat162float(((const __hip_bfloat16*)sg.src)[(long)r * sg.C + c]);
      __hip_bfloat16 h = __float2bfloat16(v);
      long d = (long)c * sg.ld + sg.off + r;
      sg.hi[d] = h;
      sg.lo[d] = __float2bfloat16(v - __bfloat162float(h));
    }
  }
}

// ---- wt_nat[r][f][h] = sum_b comp[r,b]*basis[b][f][h] ------------------------
__global__ __launch_bounds__(256) void wt_gemm(
    const float* __restrict__ basis, const float* __restrict__ comp,
    float* __restrict__ wt_nat) {
  __shared__ float cs[RR * NBASE];
  int tid = threadIdx.x;
  for (int i = tid; i < RR * NBASE; i += 256) cs[i] = comp[i];
  __syncthreads();
  long col = (long)blockIdx.x * 256 + tid;
  float acc[RR] = {};
  for (int b = 0; b < NBASE; ++b) {
    float v = basis[(long)b * 131072 + col];
#pragma unroll
    for (int r = 0; r < RR; ++r) acc[r] += cs[r * NBASE + b] * v;
  }
#pragma unroll
  for (int r = 0; r < RR; ++r) wt_nat[(long)r * 131072 + col] = acc[r];
}

// ---- wt_nat [16][512][256] (r,f,h) -> wtc[(r*256+h)][512] hi/lo --------------
__global__ __launch_bounds__(256) void wt_transpose(
    const float* __restrict__ wt_nat,
    __hip_bfloat16* __restrict__ hi, __hip_bfloat16* __restrict__ lo) {
  __shared__ float t[32][33];
  const int r = blockIdx.z;
  const int f0 = blockIdx.y * 32, h0 = blockIdx.x * 32;
  const int c = threadIdx.x & 31, rw = threadIdx.x >> 5;
  const float* src = wt_nat + ((long)r * 512 + f0) * 256 + h0;
#pragma unroll
  for (int i = 0; i < 4; ++i)
    t[rw + i * 8][c] = src[(long)(rw + i * 8) * 256 + c];
  __syncthreads();
#pragma unroll
  for (int i = 0; i < 4; ++i) {
    int hh = rw + i * 8;
    float v = t[c][hh];
    long orow = (long)(r * 256 + h0 + hh) * 512 + f0 + c;
    __hip_bfloat16 hv = __float2bfloat16(v);
    hi[orow] = hv;
    lo[orow] = __float2bfloat16(v - __bfloat162float(hv));
  }
}

// ---------------- async global->LDS helper ------------------------------------
__device__ __forceinline__ void gload_lds16(const void* g, void* l) {
  __builtin_amdgcn_global_load_lds(
      (const __attribute__((address_space(1))) unsigned int*)g,
      (__attribute__((address_space(3))) unsigned int*)l, 16, 0, 0);
}

// ---------------- fused dual-precision MFMA GEMM (128x128, 2-phase) -----------
// Used for all GEMMs except the big xw GEMM. At 3 blocks/CU its staging is
// TLP-hidden — beats 1-block/CU exact-fit structures for K-heavy small-N
// shapes (r9 lesson: mfma_step7 256x128 @1/CU regressed vs this @3/CU).
__global__ __launch_bounds__(256, 3) void mfma_dual(
    const __hip_bfloat16* __restrict__ A, const __hip_bfloat16* __restrict__ Alo,
    const __hip_bfloat16* __restrict__ Bt, const __hip_bfloat16* __restrict__ Btlo,
    const float* __restrict__ bias, float* __restrict__ C, float* __restrict__ Ct,
    __hip_bfloat16* __restrict__ Chi, __hip_bfloat16* __restrict__ Clo,
    __hip_bfloat16* __restrict__ Chi2, __hip_bfloat16* __restrict__ Clo2,
    int K, int ldc, long sA, long sB, long sC, int flags) {
  __shared__ __hip_bfloat16 Ah[128 * 32];
  __shared__ __hip_bfloat16 Bh[128 * 32];
  __shared__ __hip_bfloat16 Al[128 * 32];
  __shared__ __hip_bfloat16 Bl[128 * 32];
  const int tid = threadIdx.x;
  const int w = tid >> 6, lane = tid & 63;
  const long z = blockIdx.z;
  const long row0 = (long)blockIdx.y * 128, col0 = (long)blockIdx.x * 128;
  const int wm = w & 1, wn = w >> 1;
  const int srow0 = (w * 128 + lane) >> 2;
  const int srow1 = (w * 128 + 64 + lane) >> 2;
  const int kch = (lane & 3) * 8;
  const int fr = lane & 15, q = lane >> 4;
  const bool hasAlo = (Alo != nullptr);
  const __hip_bfloat16* Az = A + z * sA;
  const __hip_bfloat16* Alz = hasAlo ? (Alo + z * sA) : nullptr;
  const __hip_bfloat16* Bz = Bt + z * sB;
  const __hip_bfloat16* Blz = Btlo + z * sB;
  const long aoff0 = (row0 + srow0) * K + kch, aoff1 = (row0 + srow1) * K + kch;
  const long boff0 = (col0 + srow0) * K + kch, boff1 = (col0 + srow1) * K + kch;
  f32x4 acc[4][4] = {};
  for (int k0 = 0; k0 < K; k0 += 32) {
    gload_lds16(Az + aoff0 + k0, Ah + w * 1024);
    gload_lds16(Az + aoff1 + k0, Ah + w * 1024 + 512);
    gload_lds16(Bz + boff0 + k0, Bh + w * 1024);
    gload_lds16(Bz + boff1 + k0, Bh + w * 1024 + 512);
    gload_lds16(Blz + boff0 + k0, Bl + w * 1024);
    gload_lds16(Blz + boff1 + k0, Bl + w * 1024 + 512);
    if (hasAlo) {
      gload_lds16(Alz + aoff0 + k0, Al + w * 1024);
      gload_lds16(Alz + aoff1 + k0, Al + w * 1024 + 512);
    }
    __syncthreads();
    bf16x8 ah[4], bh[4], bl[4];
#pragma unroll
    for (int i = 0; i < 4; ++i) {
      ah[i] = *(const bf16x8*)&Ah[(wm * 64 + i * 16 + fr) * 32 + q * 8];
      bh[i] = *(const bf16x8*)&Bh[(wn * 64 + i * 16 + fr) * 32 + q * 8];
      bl[i] = *(const bf16x8*)&Bl[(wn * 64 + i * 16 + fr) * 32 + q * 8];
    }
#pragma unroll
    for (int i = 0; i < 4; ++i)
#pragma unroll
      for (int j = 0; j < 4; ++j) {
        acc[i][j] = __builtin_amdgcn_mfma_f32_16x16x32_bf16(ah[i], bh[j], acc[i][j], 0, 0, 0);
        acc[i][j] = __builtin_amdgcn_mfma_f32_16x16x32_bf16(ah[i], bl[j], acc[i][j], 0, 0, 0);
      }
    if (hasAlo) {
      bf16x8 al[4];
#pragma unroll
      for (int i = 0; i < 4; ++i)
        al[i] = *(const bf16x8*)&Al[(wm * 64 + i * 16 + fr) * 32 + q * 8];
#pragma unroll
      for (int i = 0; i < 4; ++i)
#pragma unroll
        for (int j = 0; j < 4; ++j)
          acc[i][j] = __builtin_amdgcn_mfma_f32_16x16x32_bf16(al[i], bh[j], acc[i][j], 0, 0, 0);
    }
    __syncthreads();
  }
  const int cr = (lane >> 4) * 4, cc = lane & 15;
  float* Cz = C ? (C + z * sC) : nullptr;
  __hip_bfloat16* Chz = Chi ? (Chi + z * sC) : nullptr;
  __hip_bfloat16* Clz = Clo ? (Clo + z * sC) : nullptr;
#pragma unroll
  for (int i = 0; i < 4; ++i) {
    long rbase = row0 + wm * 64 + i * 16 + cr;
#pragma unroll
    for (int j = 0; j < 4; ++j) {
      long col = col0 + wn * 64 + j * 16 + cc;
      float bv = (flags & FLAG_BIAS) ? bias[col] : 0.f;
#pragma unroll
      for (int r = 0; r < 4; ++r) {
        float v = acc[i][j][r] + bv;
        if (flags & FLAG_RELU) v = fmaxf(v, 0.f);
        if (flags & FLAG_TANH) v = tanhf(v);
        long row = rbase + r;
        if ((flags & FLAG_TAIL2) && col >= 768) {
          long off2 = (row >> 8) * 65536 + (col - 768) * 256 + (row & 255);
          __hip_bfloat16 hv = __float2bfloat16(v);
          Chi2[off2] = hv;
          Clo2[off2] = __float2bfloat16(v - __bfloat162float(hv));
        } else if (flags & FLAG_SPLITOUT) {
          long off = row * ldc + col;
          __hip_bfloat16 hv = __float2bfloat16(v);
          Chz[off] = hv;
          Clz[off] = __float2bfloat16(v - __bfloat162float(hv));
        } else if ((flags & FLAG_TAILOUT) && col >= 4096) {
          Ct[row * 256 + (col - 4096)] = v;
        } else {
          Cz[row * ldc + col] = v;
        }
      }
    }
  }
}

// ---------------- 256x256 dual-precision MFMA GEMM (xw only) ------------------
// r7/r8: ~104us combined, MfmaUtil 42%, WRITE full-line. Round-11: launched
// as TWO half-N (2048-col) launches of grid 8x32 = 256 blocks = exactly one
// generation each — perf-neutral (same 2 generations of work) but lets the
// rocprof top-5 surface the OTHER dispatches (gathers etc.), which have been
// hidden behind this kernel's >=5 replay instances since r7.
__device__ __forceinline__ void rd4(bf16x8 (&d)[4], const __hip_bfloat16* t,
                                    int rbase, int ro) {
#pragma unroll
  for (int i = 0; i < 4; ++i)
    d[i] = *(const bf16x8*)&t[(rbase + i * 16) * 32 + ro];
}

__device__ __forceinline__ void mm16(f32x4 (&acc)[8][4], int g,
                                     const bf16x8 (&a)[4], const bf16x8 (&b)[4]) {
#pragma unroll
  for (int i = 0; i < 4; ++i)
#pragma unroll
    for (int j = 0; j < 4; ++j)
      acc[g * 4 + i][j] =
          __builtin_amdgcn_mfma_f32_16x16x32_bf16(a[i], b[j], acc[g * 4 + i][j], 0, 0, 0);
}

__global__ __launch_bounds__(512, 2) void mfma_dual8(
    const __hip_bfloat16* __restrict__ A, const __hip_bfloat16* __restrict__ Alo,
    const __hip_bfloat16* __restrict__ Bt, const __hip_bfloat16* __restrict__ Btlo,
    const float* __restrict__ bias, float* __restrict__ C,
    int K, int ldc, int NT) {
  __shared__ __hip_bfloat16 sm[2][4][256 * 32];  // 128 KiB, [buf][Ah,Bh,Al,Bl]
  const int tid = threadIdx.x;
  const int w = tid >> 6, lane = tid & 63;
  const int wm = w >> 2, wn = w & 3;
  // T1: XCD-aware block swizzle (nwg = 256, % 8 == 0)
  const int nwg = gridDim.x * gridDim.y;
  const int bid = blockIdx.y * gridDim.x + blockIdx.x;
  const int swz = (bid & 7) * (nwg >> 3) + (bid >> 3);
  const int ty = swz % gridDim.y, tx = swz / gridDim.y;  // col-major: B-panel/XCD
  const long row0 = (long)ty * 256, col0 = (long)tx * 256;
  const int urow = tid >> 2;
  const int qg = (tid & 3) ^ ((tid >> 3) & 3);
  const long ga0 = (row0 + urow) * (long)K + qg * 8, ga1 = ga0 + 128L * K;
  const long gb0 = (col0 + urow) * (long)K + qg * 8, gb1 = gb0 + 128L * K;
  const int fr = lane & 15, q = lane >> 4;
  const int ro = fr * 32 + ((q ^ ((fr >> 1) & 3)) << 3);
  const int arow = wm * 128, brow = wn * 64;
  const int lw = w * 512;  // wave-uniform LDS chunk within a unit-half
  f32x4 acc[8][4] = {};

  auto stage = [&](int b, long k) {
    gload_lds16(A + ga0 + k, &sm[b][0][lw]);
    gload_lds16(A + ga1 + k, &sm[b][0][4096 + lw]);
    gload_lds16(Bt + gb0 + k, &sm[b][1][lw]);
    gload_lds16(Bt + gb1 + k, &sm[b][1][4096 + lw]);
    gload_lds16(Alo + ga0 + k, &sm[b][2][lw]);
    gload_lds16(Alo + ga1 + k, &sm[b][2][4096 + lw]);
    gload_lds16(Btlo + gb0 + k, &sm[b][3][lw]);
    gload_lds16(Btlo + gb1 + k, &sm[b][3][4096 + lw]);
  };

  // prologue: stage K-tile 0 into buf 0
  stage(0, 0);
  asm volatile("s_waitcnt vmcnt(0)" ::: "memory");
  __builtin_amdgcn_s_barrier();

  for (int t = 0; t < NT; ++t) {
    const int cur = t & 1, nxt = cur ^ 1;
    if (t + 1 < NT) stage(nxt, (long)(t + 1) << 5);
    const __hip_bfloat16* sA = sm[cur][0];
    const __hip_bfloat16* sB = sm[cur][1];
    const __hip_bfloat16* sAl = sm[cur][2];
    const __hip_bfloat16* sBl = sm[cur][3];
    bf16x8 bh[4], bl[4], a0[4], a1[4];
    rd4(bh, sB, brow, ro);
    rd4(bl, sBl, brow, ro);
    rd4(a0, sA, arow, ro);
    rd4(a1, sA, arow + 64, ro);
    __builtin_amdgcn_s_setprio(1);
    mm16(acc, 0, a0, bh);
    mm16(acc, 1, a1, bh);
    mm16(acc, 0, a0, bl);
    mm16(acc, 1, a1, bl);
    __builtin_amdgcn_s_setprio(0);
    rd4(a0, sAl, arow, ro);
    rd4(a1, sAl, arow + 64, ro);
    __builtin_amdgcn_s_setprio(1);
    mm16(acc, 0, a0, bh);
    mm16(acc, 1, a1, bh);
    __builtin_amdgcn_s_setprio(0);
    asm volatile("s_waitcnt vmcnt(0)" ::: "memory");
    __builtin_amdgcn_s_barrier();
  }

  // ---- epilogue: full-line stores via LDS slab transpose (write-allocate fix)
  float* ep = (float*)&sm[0][0][0];
  const int EPLD = 260;
  float bvj[4];
#pragma unroll
  for (int j = 0; j < 4; ++j) bvj[j] = bias[col0 + wn * 64 + j * 16 + fr];
  const int band = tid >> 8, tl = tid & 255;
#pragma unroll
  for (int i = 0; i < 8; ++i) {
    __builtin_amdgcn_s_barrier();  // LDS free (K-loop or previous slab done)
#pragma unroll
    for (int j = 0; j < 4; ++j) {
      int colt = wn * 64 + j * 16 + fr;
#pragma unroll
      for (int r = 0; r < 4; ++r)
        ep[(wm * 16 + q * 4 + r) * EPLD + colt] = acc[i][j][r] + bvj[j];
    }
    __builtin_amdgcn_s_barrier();
#pragma unroll
    for (int s = 0; s < 4; ++s) {
      int idx = s * 256 + tl;
      int rw = idx >> 6, c4 = idx & 63;
      float4 v = *(const float4*)&ep[(band * 16 + rw) * EPLD + c4 * 4];
      long grow = row0 + band * 128 + i * 16 + rw;
      *(float4*)&C[grow * (long)ldc + col0 + c4 * 4] = v;
    }
  }
}

// ---------------- edge kernels: CSR build + gathers ----------------------------
__global__ __launch_bounds__(256) void count_edges(
    const int* __restrict__ ei, const int* __restrict__ et, float* __restrict__ cnt) {
  int e = blockIdx.x * 256 + threadIdx.x;
  if (e < EE) atomicAdd(&cnt[ei[EE + e] * RR + et[e]], 1.0f);
}

__global__ __launch_bounds__(256) void scan_rowptr(
    const float* __restrict__ cntf, int* __restrict__ rowptr, int* __restrict__ fill) {
  __shared__ int part[256];
  int tid = threadIdx.x;
  int base = tid * 32;
  int local[32];
  int s = 0;
  for (int i = 0; i < 32; ++i) {
    local[i] = s;
    const float* c = &cntf[(base + i) * RR];
    int d = 0;
#pragma unroll
    for (int r = 0; r < RR; ++r) d += (int)c[r];
    s += d;
  }
  part[tid] = s;
  __syncthreads();
  for (int off = 1; off < 256; off <<= 1) {
    int v = (tid >= off) ? part[tid - off] : 0;
    __syncthreads();
    part[tid] += v;
    __syncthreads();
  }
  int prev = (tid == 0) ? 0 : part[tid - 1];
  for (int i = 0; i < 32; ++i) rowptr[base + i] = prev + local[i];
  if (tid == 255) rowptr[8192] = part[255];
  for (int i = tid; i < 8192; i += 256) fill[i] = 0;
}

__global__ __launch_bounds__(256) void edge_fill(
    const int* __restrict__ ei, const int* __restrict__ et,
    const int* __restrict__ rowptr, int* __restrict__ fill, int* __restrict__ eidx) {
  int e = blockIdx.x * 256 + threadIdx.x;
  if (e < EE) {
    int dst = ei[EE + e];
    int pos = rowptr[dst] + atomicAdd(&fill[dst], 1);
    eidx[pos] = ei[e] | (et[e] << 16);
  }
}

// out1 += mean-agg; emit split into a2o1 cols 256:512. Wave-split float4
// gather: wave w owns edges i%4==w, lane l covers cols 4l..4l+3.
__global__ __launch_bounds__(256) void rgcn_gather(
    const int* __restrict__ rowptr, const int* __restrict__ eidx,
    const float* __restrict__ cntf, const float* __restrict__ xw,
    float* __restrict__ out1, __hip_bfloat16* __restrict__ a2o1_hi,
    __hip_bfloat16* __restrict__ a2o1_lo) {
  const int dst = blockIdx.x;
  const int tid = threadIdx.x;
  const int w = tid >> 6, lane = tid & 63;
  const int c4 = lane * 4;
  __shared__ float inv[RR];
  __shared__ int se[256];
  __shared__ float part[3][256];
  if (tid < RR) inv[tid] = 1.0f / fmaxf(cntf[dst * RR + tid], 1.0f);
  const int beg = rowptr[dst], end = rowptr[dst + 1];
  float4 a = make_float4(0.f, 0.f, 0.f, 0.f);
  for (int c0 = beg; c0 < end; c0 += 256) {
    int n = min(256, end - c0);
    __syncthreads();
    if (tid < n) se[tid] = eidx[c0 + tid];
    __syncthreads();
    int i = w;
    for (; i + 4 < n; i += 8) {
      int p0 = se[i], p1 = se[i + 4];
      float4 v0 = *(const float4*)&xw[((long)(p0 & 0xFFFF) << 12) + ((p0 >> 16) << 8) + c4];
      float4 v1 = *(const float4*)&xw[((long)(p1 & 0xFFFF) << 12) + ((p1 >> 16) << 8) + c4];
      float s0 = inv[p0 >> 16], s1 = inv[p1 >> 16];
      a.x += v0.x * s0 + v1.x * s1;
      a.y += v0.y * s0 + v1.y * s1;
      a.z += v0.z * s0 + v1.z * s1;
      a.w += v0.w * s0 + v1.w * s1;
    }
    for (; i < n; i += 4) {
      int p0 = se[i];
      float4 v0 = *(const float4*)&xw[((long)(p0 & 0xFFFF) << 12) + ((p0 >> 16) << 8) + c4];
      float s0 = inv[p0 >> 16];
      a.x += v0.x * s0;
      a.y += v0.y * s0;
      a.z += v0.z * s0;
      a.w += v0.w * s0;
    }
  }
  __syncthreads();
  if (w) *(float4*)&part[w - 1][c4] = a;
  __syncthreads();
  if (w == 0) {
    float4 p0 = *(const float4*)&part[0][c4];
    float4 p1 = *(const float4*)&part[1][c4];
    float4 p2 = *(const float4*)&part[2][c4];
    long ob = ((long)dst << 8) + c4;
    float4 o = *(const float4*)&out1[ob];
    float t0 = o.x + a.x + p0.x + p1.x + p2.x;
    float t1 = o.y + a.y + p0.y + p1.y + p2.y;
    float t2 = o.z + a.z + p0.z + p1.z + p2.z;
    float t3 = o.w + a.w + p0.w + p1.w + p2.w;
    *(float4*)&out1[ob] = make_float4(t0, t1, t2, t3);
    __hip_bfloat16 h0 = __float2bfloat16(t0), h1 = __float2bfloat16(t1),
                   h2 = __float2bfloat16(t2), h3 = __float2bfloat16(t3);
    ushort4 hv = {*(unsigned short*)&h0, *(unsigned short*)&h1,
                  *(unsigned short*)&h2, *(unsigned short*)&h3};
    __hip_bfloat16 l0 = __float2bfloat16(t0 - __bfloat162float(h0)),
                   l1 = __float2bfloat16(t1 - __bfloat162float(h1)),
                   l2 = __float2bfloat16(t2 - __bfloat162float(h2)),
                   l3 = __float2bfloat16(t3 - __bfloat162float(h3));
    ushort4 lv = {*(unsigned short*)&l0, *(unsigned short*)&l1,
                  *(unsigned short*)&l2, *(unsigned short*)&l3};
    long d = (long)dst * 512 + 256 + c4;
    *(ushort4*)(a2o1_hi + d) = hv;
    *(ushort4*)(a2o1_lo + d) = lv;
  }
}

// a2o1 cols 0:256 = sum_{src->dst} out1[src] (wave-split float4, same scheme)
__global__ __launch_bounds__(256) void graphconv_gather(
    const int* __restrict__ rowptr, const int* __restrict__ eidx,
    const float* __restrict__ out1, __hip_bfloat16* __restrict__ a2o1_hi,
    __hip_bfloat16* __restrict__ a2o1_lo) {
  const int dst = blockIdx.x;
  const int tid = threadIdx.x;
  const int w = tid >> 6, lane = tid & 63;
  const int c4 = lane * 4;
  __shared__ int se[256];
  __shared__ float part[3][256];
  const int beg = rowptr[dst], end = rowptr[dst + 1];
  float4 a = make_float4(0.f, 0.f, 0.f, 0.f);
  for (int c0 = beg; c0 < end; c0 += 256) {
    int n = min(256, end - c0);
    __syncthreads();
    if (tid < n) se[tid] = eidx[c0 + tid];
    __syncthreads();
    int i = w;
    for (; i + 4 < n; i += 8) {
      float4 v0 = *(const float4*)&out1[((long)(se[i] & 0xFFFF) << 8) + c4];
      float4 v1 = *(const float4*)&out1[((long)(se[i + 4] & 0xFFFF) << 8) + c4];
      a.x += v0.x + v1.x;
      a.y += v0.y + v1.y;
      a.z += v0.z + v1.z;
      a.w += v0.w + v1.w;
    }
    for (; i < n; i += 4) {
      float4 v0 = *(const float4*)&out1[((long)(se[i] & 0xFFFF) << 8) + c4];
      a.x += v0.x;
      a.y += v0.y;
      a.z += v0.z;
      a.w += v0.w;
    }
  }
  __syncthreads();
  if (w) *(float4*)&part[w - 1][c4] = a;
  __syncthreads();
  if (w == 0) {
    float4 p0 = *(const float4*)&part[0][c4];
    float4 p1 = *(const float4*)&part[1][c4];
    float4 p2 = *(const float4*)&part[2][c4];
    float t0 = a.x + p0.x + p1.x + p2.x;
    float t1 = a.y + p0.y + p1.y + p2.y;
    float t2 = a.z + p0.z + p1.z + p2.z;
    float t3 = a.w + p0.w + p1.w + p2.w;
    __hip_bfloat16 h0 = __float2bfloat16(t0), h1 = __float2bfloat16(t1),
                   h2 = __float2bfloat16(t2), h3 = __float2bfloat16(t3);
    ushort4 hv = {*(unsigned short*)&h0, *(unsigned short*)&h1,
                  *(unsigned short*)&h2, *(unsigned short*)&h3};
    __hip_bfloat16 l0 = __float2bfloat16(t0 - __bfloat162float(h0)),
                   l1 = __float2bfloat16(t1 - __bfloat162float(h1)),
                   l2 = __float2bfloat16(t2 - __bfloat162float(h2)),
                   l3 = __float2bfloat16(t3 - __bfloat162float(h3));
    ushort4 lv = {*(unsigned short*)&l0, *(unsigned short*)&l1,
                  *(unsigned short*)&l2, *(unsigned short*)&l3};
    long d = (long)dst * 512 + c4;
    *(ushort4*)(a2o1_hi + d) = hv;
    *(ushort4*)(a2o1_lo + d) = lv;
  }
}

// ---------------- softmax over last dim (256), bf16 weights out ---------------
__global__ __launch_bounds__(256) void softmax256(const float* __restrict__ S,
                                                  __hip_bfloat16* __restrict__ Ab) {
  __shared__ float red[256];
  long row = blockIdx.x;
  const float* p = S + row * 256;
  int t = threadIdx.x;
  float v = p[t];
  red[t] = v;
  __syncthreads();
  for (int s = 128; s > 0; s >>= 1) {
    if (t < s) red[t] = fmaxf(red[t], red[t + s]);
    __syncthreads();
  }
  float m = red[0];
  __syncthreads();
  float e = __expf(v - m);
  red[t] = e;
  __syncthreads();
  for (int s = 128; s > 0; s >>= 1) {
    if (t < s) red[t] += red[t + s];
    __syncthreads();
  }
  Ab[row * 256 + t] = __float2bfloat16(e / red[0]);
}

// ---------------- logits + log_softmax over batch axis (faithful dim=1) -------
__global__ __launch_bounds__(256) void logits_lsm(
    const float* __restrict__ hidden, const float* __restrict__ w_fc,
    const float* __restrict__ b_fc, void* __restrict__ out_v,
    const int* __restrict__ flag) {
  __shared__ float wf[256 * 7];
  __shared__ float lg[224];
  __shared__ float corr[7];
  int t = blockIdx.x;
  int tid = threadIdx.x;
  for (int i = tid; i < 256 * 7; i += 256) wf[i] = w_fc[i];
  __syncthreads();
  if (tid < 224) {
    int b = tid / 7, c = tid % 7;
    const float* hr = hidden + ((long)((b << 8) + t) << 8);
    float s = b_fc[c];
    for (int k = 0; k < 256; ++k) s += hr[k] * wf[k * 7 + c];
    lg[tid] = s;
  }
  __syncthreads();
  if (tid < 7) {
    float m = -1e30f;
    for (int b = 0; b < BB; ++b) m = fmaxf(m, lg[b * 7 + tid]);
    float sum = 0.f;
    for (int b = 0; b < BB; ++b) sum += __expf(lg[b * 7 + tid] - m);
    corr[tid] = m + logf(sum);
  }
  __syncthreads();
  if (tid < 224) {
    float v = lg[tid] - corr[tid % 7];
    if (flag[0]) ((float*)out_v)[t * 224 + tid] = v;
    else ((__hip_bfloat16*)out_v)[t * 224 + tid] = __float2bfloat16(v);
  }
}

extern "C" void kernel_launch(void* const* d_in, const int* in_sizes, int n_in,
                              void* d_out, int out_size, void* d_ws, size_t ws_size,
                              hipStream_t stream) {
  const int* ei = (const int*)d_in[1];
  const int* et = (const int*)d_in[3];

  float* ws = (float*)d_ws;
  int* flag = (int*)d_ws;
  float* p = ws + 16;
  auto alloc = [&](long nf) { float* r = p; p += nf; return r; };
  float* w_fc_f = alloc(1792);
  float* b_rel_f = alloc(256);
  float* biasx = alloc(4352);                                    // [0..4095]=0, tail=bias1
  float* battx = alloc(1024);                                    // [0..767]=b_att, rest 0
  float* b_lin_f = alloc(256);
  float* b_fc_f = alloc(16);
  __hip_bfloat16* x_hi = (__hip_bfloat16*)alloc(2097152);        // [8192][512]
  __hip_bfloat16* x_lo = (__hip_bfloat16*)alloc(2097152);
  __hip_bfloat16* wae_hi = (__hip_bfloat16*)alloc(393216);       // [1024][768] = [w_att|w_lin]^T
  __hip_bfloat16* wae_lo = (__hip_bfloat16*)alloc(393216);
  __hip_bfloat16* wrr_hi = (__hip_bfloat16*)alloc(65536);        // [256][512] = [w_rel;w_root]^T
  __hip_bfloat16* wrr_lo = (__hip_bfloat16*)alloc(65536);
  __hip_bfloat16* wtc_hi = (__hip_bfloat16*)alloc(1114112);      // [4352][512]
  __hip_bfloat16* wtc_lo = (__hip_bfloat16*)alloc(1114112);
  float* basis_f = alloc(3932160);
  float* comp_f = alloc(512);
  float* xw = alloc(33554432);   // fp32 [8192][4096]; overlays below
  float* cnt = alloc(131072);
  float* out1 = alloc(2097152);
  __hip_bfloat16* a2o1_hi = (__hip_bfloat16*)alloc(2097152);     // [8192][512]
  __hip_bfloat16* a2o1_lo = (__hip_bfloat16*)alloc(2097152);
  float* hidden = alloc(2097152);
  int* rowptr = (int*)alloc(8208);
  int* fillc = (int*)alloc(8192);
  int* eidx = (int*)alloc(262144);
  // wt_nat overlays head of xw (consumed by wt_transpose before xw is written)
  float* wt_nat = xw;                                            // [16][512][256]
  // phase B overlays the (consumed) xw region
  float* em = xw;
  __hip_bfloat16* emwT_hi = (__hip_bfloat16*)(em + 2097152);     // [32][256][256]
  __hip_bfloat16* emwT_lo = (__hip_bfloat16*)(em + 3145728);
  __hip_bfloat16* em_hi = (__hip_bfloat16*)(em + 6291456);       // [8192][768]
  __hip_bfloat16* em_lo = (__hip_bfloat16*)(em + 9437184);
  __hip_bfloat16* X_hi = (__hip_bfloat16*)(em + 12582912);
  __hip_bfloat16* X_lo = (__hip_bfloat16*)(em + 15728640);
  float* scores = em + 18874368;                                 // 2,097,152 f
  __hip_bfloat16* a_b16 = (__hip_bfloat16*)(em + 20971520);      // 1,048,576 f

  // 0. dtype detect + one unified prep launch
  detect_dtype<<<1, 256, 0, stream>>>((const unsigned short*)d_in[0], flag);
  PTable T{};
  long tot = 0;
  int ns = 0;
  auto segL = [&](const void* s, float* d, __hip_bfloat16* hi, __hip_bfloat16* lo,
                  __hip_bfloat16* hi2, __hip_bfloat16* lo2, long n, int z) {
    T.seg[ns] = PSeg{s, d, hi, lo, hi2, lo2, n, 0, 0, 0, 0, 0, z};
    ns++; tot += n;
  };
  auto segT = [&](const void* s, __hip_bfloat16* hi, __hip_bfloat16* lo,
                  int R, int C, int ld, int off) {
    T.seg[ns] = PSeg{s, nullptr, hi, lo, nullptr, nullptr, (long)R * C, R, C, ld, off, 1, 0};
    ns++; tot += (long)R * C;
  };
  segL(d_in[0], nullptr, x_hi, x_lo, nullptr, nullptr, NN * FF, 0);
  segL(d_in[8], basis_f, nullptr, nullptr, nullptr, nullptr, NBASE * FF * HH, 0);
  segL(d_in[9], comp_f, nullptr, nullptr, nullptr, nullptr, RR * NBASE, 0);
  segL(d_in[13], b_rel_f, nullptr, nullptr, nullptr, nullptr, HH, 0);
  segL(d_in[16], battx, nullptr, nullptr, nullptr, nullptr, DD, 0);
  segL(nullptr, battx + DD, nullptr, nullptr, nullptr, nullptr, 256, 1);
  segL(d_in[18], b_lin_f, nullptr, nullptr, nullptr, nullptr, HH, 0);
  segL(d_in[19], w_fc_f, nullptr, nullptr, nullptr, nullptr, HH * CC, 0);
  segL(d_in[20], b_fc_f, nullptr, nullptr, nullptr, nullptr, CC, 0);
  segL(nullptr, biasx, nullptr, nullptr, nullptr, nullptr, 4096, 1);
  segL(d_in[11], biasx + 4096, nullptr, nullptr, nullptr, nullptr, HH, 0);
  segT(d_in[15], wae_hi, wae_lo, DD, DD, DD, 0);                 // w_att^T -> rows 0:768
  segT(d_in[17], wae_hi + 768 * 768, wae_lo + 768 * 768, DD, HH, DD, 0);  // w_lin^T -> rows 768:1024
  segT(d_in[10], wtc_hi + 4096 * 512, wtc_lo + 4096 * 512, FF, HH, FF, 0);  // root1^T
  segT(d_in[12], wrr_hi, wrr_lo, HH, HH, 512, 0);                // w_rel^T
  segT(d_in[14], wrr_hi, wrr_lo, HH, HH, 512, 256);              // w_root^T
  T.count = ns;
  T.total = tot;
  prep_all<<<4096, 256, 0, stream>>>(T, flag);

  // 1. Wt: coalesced GEMM into natural layout, then LDS-tiled transpose + split
  wt_gemm<<<131072 / 256, 256, 0, stream>>>(basis_f, comp_f, wt_nat);
  wt_transpose<<<dim3(8, 16, 16), 256, 0, stream>>>(wt_nat, wtc_hi, wtc_lo);
  // 2. xw = x @ W (cols 0:4096) as TWO half-N launches, each grid 8x32 = 256
  //    blocks = exactly one generation (perf-neutral vs one 512-block launch;
  //    makes the other pipeline dispatches visible in rocprof top-5).
  mfma_dual8<<<dim3(8, 32), 512, 0, stream>>>(
      x_hi, x_lo, wtc_hi, wtc_lo, biasx, xw, FF, 4096, FF / 32);
  mfma_dual8<<<dim3(8, 32), 512, 0, stream>>>(
      x_hi, x_lo, wtc_hi + 2048 * 512, wtc_lo + 2048 * 512, biasx + 2048,
      xw + 2048, FF, 4096, FF / 32);
  // 2b. out1 = x @ root1 + bias1 (the former TAILOUT columns), small 2-phase GEMM
  mfma_dual<<<dim3(2, 64, 1), 256, 0, stream>>>(
      x_hi, x_lo, wtc_hi + 4096 * 512, wtc_lo + 4096 * 512, biasx + 4096,
      out1, nullptr, nullptr, nullptr, nullptr, nullptr, FF, HH, 0, 0, 0, FLAG_BIAS);
  // 3. CSR build
  hipMemsetAsync(cnt, 0, 131072 * sizeof(float), stream);
  count_edges<<<EE / 256, 256, 0, stream>>>(ei, et, cnt);
  scan_rowptr<<<1, 256, 0, stream>>>(cnt, rowptr, fillc);
  edge_fill<<<EE / 256, 256, 0, stream>>>(ei, et, rowptr, fillc, eidx);
  // 4/5. aggregations (gather); emit [agg2|out1] hi/lo as out2-GEMM A operand
  rgcn_gather<<<NN, 256, 0, stream>>>(rowptr, eidx, cnt, xw, out1, a2o1_hi, a2o1_lo);
  graphconv_gather<<<NN, 256, 0, stream>>>(rowptr, eidx, out1, a2o1_hi, a2o1_lo);
  // 6. em cols 0:512 = x (split, from x_hi/x_lo after xw is dead)
  extern __global__ void copy_xsplit_k(const __hip_bfloat16*, const __hip_bfloat16*,
                                       __hip_bfloat16*, __hip_bfloat16*);
  copy_xsplit_k<<<(NN * FF) / 256, 256, 0, stream>>>(x_hi, x_lo, em_hi, em_lo);
  // 6b. out2 -> em cols 512:768 via split-MFMA
  mfma_dual<<<dim3(2, 64, 1), 256, 0, stream>>>(
      a2o1_hi, a2o1_lo, wrr_hi, wrr_lo, b_rel_f, nullptr, nullptr,
      em_hi + 512, em_lo + 512, nullptr, nullptr, 512, DD, 0, 0, 0,
      FLAG_BIAS | FLAG_SPLITOUT);
  // 7. [X | emwT] = em @ [w_att | w_lin] (+b_att|0); cols>=768 -> transposed split
  //    2-phase mfma_dual @ 3 blocks/CU (r9: 1-block/CU 256x128 variant regressed).
  mfma_dual<<<dim3(8, 64, 1), 256, 0, stream>>>(
      em_hi, em_lo, wae_hi, wae_lo, battx, nullptr, nullptr, X_hi, X_lo,
      emwT_hi, emwT_lo, DD, DD, 0, 0, 0, FLAG_BIAS | FLAG_SPLITOUT | FLAG_TAIL2);
  // 8. scores = tanh(X_b . em_b^T) (batched, fp32 out)
  mfma_dual<<<dim3(2, 2, BB), 256, 0, stream>>>(
      X_hi, X_lo, em_hi, em_lo, nullptr, scores, nullptr, nullptr, nullptr,
      nullptr, nullptr, DD, LL, (long)LL * DD, (long)LL * DD, (long)LL * LL, FLAG_TANH);
  // 9. softmax over s -> bf16 attention weights
  softmax256<<<BB * LL, 256, 0, stream>>>(scores, a_b16);
  // 10. hidden = relu(a @ emwT + b_lin)
  mfma_dual<<<dim3(2, 2, BB), 256, 0, stream>>>(
      a_b16, nullptr, emwT_hi, emwT_lo, b_lin_f, hidden, nullptr, nullptr, nullptr,
      nullptr, nullptr, LL, HH, (long)LL * LL, (long)LL * HH, (long)LL * HH,
      FLAG_BIAS | FLAG_RELU);
  // 11. logits + log_softmax over batch axis
  logits_lsm<<<LL, 256, 0, stream>>>(hidden, w_fc_f, b_fc_f, d_out, flag);
}

// copy x_hi/x_lo [8192][512] into em_hi/lo [8192][768] cols 0:512
__global__ __launch_bounds__(256) void copy_xsplit_k(
    const __hip_bfloat16* __restrict__ xh, const __hip_bfloat16* __restrict__ xl,
    __hip_bfloat16* __restrict__ eh, __hip_bfloat16* __restrict__ el) {
  int idx = blockIdx.x * 256 + threadIdx.x;  // 8192*512
  int n = idx >> 9, f = idx & 511;
  long d = (long)n * DD + f;
  eh[d] = xh[idx];
  el[d] = xl[idx];
}

// Round 12
// 578.944 us; speedup vs baseline: 1.2372x; 1.0701x over previous
//
#include <hip/hip_runtime.h>
#include <hip/hip_bf16.h>

// Problem constants (fixed by setup_inputs)
#define NN 8192
#define FF 512
#define HH 256
#define RR 16
#define BB 32
#define LL 256
#define CC 7
#define EE 262144
#define NBASE 30
#define DD 768

constexpr int FLAG_BIAS = 1, FLAG_RELU = 4, FLAG_TANH = 8,
              FLAG_SPLITOUT = 16, FLAG_TAILOUT = 32, FLAG_TAIL2 = 64;

typedef __attribute__((ext_vector_type(8))) short bf16x8;
typedef __attribute__((ext_vector_type(4))) float f32x4;

// ------------- dtype detection (robustness) -----------------------------------
__global__ __launch_bounds__(256) void detect_dtype(const unsigned short* __restrict__ xs,
                                                    int* __restrict__ flag) {
  __shared__ int red[256];
  int cnt = 0;
  for (int i = threadIdx.x * 2; i < 8192; i += 512) {
    unsigned short u = xs[i];
    int e = (u >> 7) & 0xFF;
    if (e >= 0xC0) cnt++;
  }
  red[threadIdx.x] = cnt;
  __syncthreads();
  for (int s = 128; s > 0; s >>= 1) {
    if (threadIdx.x < s) red[threadIdx.x] += red[threadIdx.x + s];
    __syncthreads();
  }
  if (threadIdx.x == 0) flag[0] = (red[0] > 16) ? 1 : 0;  // 1 = fp32 data
}

// ------------- unified prep: conversions + transposed splits, one launch -------
struct PSeg {
  const void* src;
  float* dst;
  __hip_bfloat16* hi;
  __hip_bfloat16* lo;
  __hip_bfloat16* hi2;   // optional second (strided) split dest (x -> em cols)
  __hip_bfloat16* lo2;
  long n;                // R*C elements
  int R, C, ld, off;     // transpose geometry (type==1)
  int type;              // 0 = linear, 1 = transpose-split
  int zero;
};
struct PTable {
  PSeg seg[16];
  int count;
  long total;
};

__global__ __launch_bounds__(256) void prep_all(PTable t, const int* __restrict__ flag) {
  const int fp32 = flag[0];
  for (long i = (long)blockIdx.x * 256 + threadIdx.x; i < t.total;
       i += (long)gridDim.x * 256) {
    long off = i;
    int s = 0;
    while (off >= t.seg[s].n) { off -= t.seg[s].n; s++; }
    const PSeg& sg = t.seg[s];
    if (sg.type == 0) {
      float v = 0.f;
      if (!sg.zero)
        v = fp32 ? ((const float*)sg.src)[off]
                 : __bfloat162float(((const __hip_bfloat16*)sg.src)[off]);
      if (sg.dst) sg.dst[off] = v;
      if (sg.hi) {
        __hip_bfloat16 h = __float2bfloat16(v);
        __hip_bfloat16 l = __float2bfloat16(v - __bfloat162float(h));
        sg.hi[off] = h;
        sg.lo[off] = l;
        if (sg.hi2) {  // x -> em cols 0:512 (row width 512 -> 768)
          long d2 = (off >> 9) * DD + (off & 511);
          sg.hi2[d2] = h;
          sg.lo2[d2] = l;
        }
      }
    } else {
      int r = (int)(off % sg.R), c = (int)(off / sg.R);
      float v = fp32 ? ((const float*)sg.src)[(long)r * sg.C + c]
                     : __bfloat162float(((const __hip_bfloat16*)sg.src)[(long)r * sg.C + c]);
      __hip_bfloat16 h = __float2bfloat16(v);
      long d = (long)c * sg.ld + sg.off + r;
      sg.hi[d] = h;
      sg.lo[d] = __float2bfloat16(v - __bfloat162float(h));
    }
  }
}

// ---- wt_nat[r][f][h] = sum_b comp[r,b]*basis[b][f][h] ------------------------
__global__ __launch_bounds__(256) void wt_gemm(
    const float* __restrict__ basis, const float* __restrict__ comp,
    float* __restrict__ wt_nat) {
  __shared__ float cs[RR * NBASE];
  int tid = threadIdx.x;
  for (int i = tid; i < RR * NBASE; i += 256) cs[i] = comp[i];
  __syncthreads();
  long col = (long)blockIdx.x * 256 + tid;
  float acc[RR] = {};
  for (int b = 0; b < NBASE; ++b) {
    float v = basis[(long)b * 131072 + col];
#pragma unroll
    for (int r = 0; r < RR; ++r) acc[r] += cs[r * NBASE + b] * v;
  }
#pragma unroll
  for (int r = 0; r < RR; ++r) wt_nat[(long)r * 131072 + col] = acc[r];
}

// ---- wt_nat [16][512][256] (r,f,h) -> wtc[(r*256+h)][512] hi/lo --------------
__global__ __launch_bounds__(256) void wt_transpose(
    const float* __restrict__ wt_nat,
    __hip_bfloat16* __restrict__ hi, __hip_bfloat16* __restrict__ lo) {
  __shared__ float t[32][33];
  const int r = blockIdx.z;
  const int f0 = blockIdx.y * 32, h0 = blockIdx.x * 32;
  const int c = threadIdx.x & 31, rw = threadIdx.x >> 5;
  const float* src = wt_nat + ((long)r * 512 + f0) * 256 + h0;
#pragma unroll
  for (int i = 0; i < 4; ++i)
    t[rw + i * 8][c] = src[(long)(rw + i * 8) * 256 + c];
  __syncthreads();
#pragma unroll
  for (int i = 0; i < 4; ++i) {
    int hh = rw + i * 8;
    float v = t[c][hh];
    long orow = (long)(r * 256 + h0 + hh) * 512 + f0 + c;
    __hip_bfloat16 hv = __float2bfloat16(v);
    hi[orow] = hv;
    lo[orow] = __float2bfloat16(v - __bfloat162float(hv));
  }
}

// ---------------- async global->LDS helper ------------------------------------
__device__ __forceinline__ void gload_lds16(const void* g, void* l) {
  __builtin_amdgcn_global_load_lds(
      (const __attribute__((address_space(1))) unsigned int*)g,
      (__attribute__((address_space(3))) unsigned int*)l, 16, 0, 0);
}

// ---------------- fused dual-precision MFMA GEMM (128x128, 2-phase) -----------
// Used for medium GEMMs with bf16-split epilogues (6b, 7).
__global__ __launch_bounds__(256, 3) void mfma_dual(
    const __hip_bfloat16* __restrict__ A, const __hip_bfloat16* __restrict__ Alo,
    const __hip_bfloat16* __restrict__ Bt, const __hip_bfloat16* __restrict__ Btlo,
    const float* __restrict__ bias, float* __restrict__ C, float* __restrict__ Ct,
    __hip_bfloat16* __restrict__ Chi, __hip_bfloat16* __restrict__ Clo,
    __hip_bfloat16* __restrict__ Chi2, __hip_bfloat16* __restrict__ Clo2,
    int K, int ldc, long sA, long sB, long sC, int flags) {
  __shared__ __hip_bfloat16 Ah[128 * 32];
  __shared__ __hip_bfloat16 Bh[128 * 32];
  __shared__ __hip_bfloat16 Al[128 * 32];
  __shared__ __hip_bfloat16 Bl[128 * 32];
  const int tid = threadIdx.x;
  const int w = tid >> 6, lane = tid & 63;
  const long z = blockIdx.z;
  const long row0 = (long)blockIdx.y * 128, col0 = (long)blockIdx.x * 128;
  const int wm = w & 1, wn = w >> 1;
  const int srow0 = (w * 128 + lane) >> 2;
  const int srow1 = (w * 128 + 64 + lane) >> 2;
  const int kch = (lane & 3) * 8;
  const int fr = lane & 15, q = lane >> 4;
  const bool hasAlo = (Alo != nullptr);
  const __hip_bfloat16* Az = A + z * sA;
  const __hip_bfloat16* Alz = hasAlo ? (Alo + z * sA) : nullptr;
  const __hip_bfloat16* Bz = Bt + z * sB;
  const __hip_bfloat16* Blz = Btlo + z * sB;
  const long aoff0 = (row0 + srow0) * K + kch, aoff1 = (row0 + srow1) * K + kch;
  const long boff0 = (col0 + srow0) * K + kch, boff1 = (col0 + srow1) * K + kch;
  f32x4 acc[4][4] = {};
  for (int k0 = 0; k0 < K; k0 += 32) {
    gload_lds16(Az + aoff0 + k0, Ah + w * 1024);
    gload_lds16(Az + aoff1 + k0, Ah + w * 1024 + 512);
    gload_lds16(Bz + boff0 + k0, Bh + w * 1024);
    gload_lds16(Bz + boff1 + k0, Bh + w * 1024 + 512);
    gload_lds16(Blz + boff0 + k0, Bl + w * 1024);
    gload_lds16(Blz + boff1 + k0, Bl + w * 1024 + 512);
    if (hasAlo) {
      gload_lds16(Alz + aoff0 + k0, Al + w * 1024);
      gload_lds16(Alz + aoff1 + k0, Al + w * 1024 + 512);
    }
    __syncthreads();
    bf16x8 ah[4], bh[4], bl[4];
#pragma unroll
    for (int i = 0; i < 4; ++i) {
      ah[i] = *(const bf16x8*)&Ah[(wm * 64 + i * 16 + fr) * 32 + q * 8];
      bh[i] = *(const bf16x8*)&Bh[(wn * 64 + i * 16 + fr) * 32 + q * 8];
      bl[i] = *(const bf16x8*)&Bl[(wn * 64 + i * 16 + fr) * 32 + q * 8];
    }
#pragma unroll
    for (int i = 0; i < 4; ++i)
#pragma unroll
      for (int j = 0; j < 4; ++j) {
        acc[i][j] = __builtin_amdgcn_mfma_f32_16x16x32_bf16(ah[i], bh[j], acc[i][j], 0, 0, 0);
        acc[i][j] = __builtin_amdgcn_mfma_f32_16x16x32_bf16(ah[i], bl[j], acc[i][j], 0, 0, 0);
      }
    if (hasAlo) {
      bf16x8 al[4];
#pragma unroll
      for (int i = 0; i < 4; ++i)
        al[i] = *(const bf16x8*)&Al[(wm * 64 + i * 16 + fr) * 32 + q * 8];
#pragma unroll
      for (int i = 0; i < 4; ++i)
#pragma unroll
        for (int j = 0; j < 4; ++j)
          acc[i][j] = __builtin_amdgcn_mfma_f32_16x16x32_bf16(al[i], bh[j], acc[i][j], 0, 0, 0);
    }
    __syncthreads();
  }
  const int cr = (lane >> 4) * 4, cc = lane & 15;
  float* Cz = C ? (C + z * sC) : nullptr;
  __hip_bfloat16* Chz = Chi ? (Chi + z * sC) : nullptr;
  __hip_bfloat16* Clz = Clo ? (Clo + z * sC) : nullptr;
#pragma unroll
  for (int i = 0; i < 4; ++i) {
    long rbase = row0 + wm * 64 + i * 16 + cr;
#pragma unroll
    for (int j = 0; j < 4; ++j) {
      long col = col0 + wn * 64 + j * 16 + cc;
      float bv = (flags & FLAG_BIAS) ? bias[col] : 0.f;
#pragma unroll
      for (int r = 0; r < 4; ++r) {
        float v = acc[i][j][r] + bv;
        if (flags & FLAG_RELU) v = fmaxf(v, 0.f);
        if (flags & FLAG_TANH) v = tanhf(v);
        long row = rbase + r;
        if ((flags & FLAG_TAIL2) && col >= 768) {
          long off2 = (row >> 8) * 65536 + (col - 768) * 256 + (row & 255);
          __hip_bfloat16 hv = __float2bfloat16(v);
          Chi2[off2] = hv;
          Clo2[off2] = __float2bfloat16(v - __bfloat162float(hv));
        } else if (flags & FLAG_SPLITOUT) {
          long off = row * ldc + col;
          __hip_bfloat16 hv = __float2bfloat16(v);
          Chz[off] = hv;
          Clz[off] = __float2bfloat16(v - __bfloat162float(hv));
        } else if ((flags & FLAG_TAILOUT) && col >= 4096) {
          Ct[row * 256 + (col - 4096)] = v;
        } else {
          Cz[row * ldc + col] = v;
        }
      }
    }
  }
}

// ---------------- 64x64-tile batched dual-precision GEMM (fp32 out) -----------
// Round-12: the scores GEMM (r11 top-5) ran 104.7us at grid 128 = 0.5 block/CU,
// Occupancy 5.4%, MfmaUtil 3.4% — latency-bound with half the chip idle. This
// variant gives batched/skinny shapes 4x the blocks: 64x64 tile, 256 thr
// (4 waves; wave w owns rows w*16, all 64 cols, acc[4]). Staging/fragment/
// C-mapping patterns copied verbatim from mfma_dual (same pass order ->
// identical accumulation numerics). fp32 output only (BIAS/RELU/TANH).
__global__ __launch_bounds__(256) void mfma_b64(
    const __hip_bfloat16* __restrict__ A, const __hip_bfloat16* __restrict__ Alo,
    const __hip_bfloat16* __restrict__ Bt, const __hip_bfloat16* __restrict__ Btlo,
    const float* __restrict__ bias, float* __restrict__ C,
    int K, int ldc, long sA, long sB, long sC, int flags) {
  __shared__ __hip_bfloat16 Ah[64 * 32];
  __shared__ __hip_bfloat16 Bh[64 * 32];
  __shared__ __hip_bfloat16 Al[64 * 32];
  __shared__ __hip_bfloat16 Bl[64 * 32];
  const int tid = threadIdx.x;
  const int w = tid >> 6, lane = tid & 63;
  const long z = blockIdx.z;
  const long row0 = (long)blockIdx.y * 64, col0 = (long)blockIdx.x * 64;
  const int srow = tid >> 2;            // staging row 0..63 (wave w: rows w*16..+15)
  const int kch = (tid & 3) * 8;
  const int fr = lane & 15, q = lane >> 4;
  const bool hasAlo = (Alo != nullptr);
  const __hip_bfloat16* Az = A + z * sA;
  const __hip_bfloat16* Alz = hasAlo ? (Alo + z * sA) : nullptr;
  const __hip_bfloat16* Bz = Bt + z * sB;
  const __hip_bfloat16* Blz = Btlo + z * sB;
  const long aoff = (row0 + srow) * (long)K + kch;
  const long boff = (col0 + srow) * (long)K + kch;
  f32x4 acc[4] = {};
  for (int k0 = 0; k0 < K; k0 += 32) {
    gload_lds16(Az + aoff + k0, Ah + w * 512);
    gload_lds16(Bz + boff + k0, Bh + w * 512);
    gload_lds16(Blz + boff + k0, Bl + w * 512);
    if (hasAlo) gload_lds16(Alz + aoff + k0, Al + w * 512);
    __syncthreads();
    bf16x8 ah, bh[4], bl[4];
    ah = *(const bf16x8*)&Ah[(w * 16 + fr) * 32 + q * 8];
#pragma unroll
    for (int j = 0; j < 4; ++j) {
      bh[j] = *(const bf16x8*)&Bh[(j * 16 + fr) * 32 + q * 8];
      bl[j] = *(const bf16x8*)&Bl[(j * 16 + fr) * 32 + q * 8];
    }
#pragma unroll
    for (int j = 0; j < 4; ++j) {
      acc[j] = __builtin_amdgcn_mfma_f32_16x16x32_bf16(ah, bh[j], acc[j], 0, 0, 0);
      acc[j] = __builtin_amdgcn_mfma_f32_16x16x32_bf16(ah, bl[j], acc[j], 0, 0, 0);
    }
    if (hasAlo) {
      bf16x8 al = *(const bf16x8*)&Al[(w * 16 + fr) * 32 + q * 8];
#pragma unroll
      for (int j = 0; j < 4; ++j)
        acc[j] = __builtin_amdgcn_mfma_f32_16x16x32_bf16(al, bh[j], acc[j], 0, 0, 0);
    }
    __syncthreads();
  }
  const long rbase = row0 + w * 16 + q * 4;
  float* Cz = C + z * sC;
#pragma unroll
  for (int j = 0; j < 4; ++j) {
    long col = col0 + j * 16 + fr;
    float bv = (flags & FLAG_BIAS) ? bias[col] : 0.f;
#pragma unroll
    for (int r = 0; r < 4; ++r) {
      float v = acc[j][r] + bv;
      if (flags & FLAG_RELU) v = fmaxf(v, 0.f);
      if (flags & FLAG_TANH) v = tanhf(v);
      Cz[(rbase + r) * (long)ldc + col] = v;
    }
  }
}

// ---------------- 256x256 dual-precision MFMA GEMM (xw only) ------------------
// r7/r8: ~104us combined, MfmaUtil 42%, WRITE full-line. Two half-N launches
// of grid 8x32 = 256 blocks = exactly one generation each (perf-neutral,
// keeps the rest of the pipeline visible in rocprof top-5).
__device__ __forceinline__ void rd4(bf16x8 (&d)[4], const __hip_bfloat16* t,
                                    int rbase, int ro) {
#pragma unroll
  for (int i = 0; i < 4; ++i)
    d[i] = *(const bf16x8*)&t[(rbase + i * 16) * 32 + ro];
}

__device__ __forceinline__ void mm16(f32x4 (&acc)[8][4], int g,
                                     const bf16x8 (&a)[4], const bf16x8 (&b)[4]) {
#pragma unroll
  for (int i = 0; i < 4; ++i)
#pragma unroll
    for (int j = 0; j < 4; ++j)
      acc[g * 4 + i][j] =
          __builtin_amdgcn_mfma_f32_16x16x32_bf16(a[i], b[j], acc[g * 4 + i][j], 0, 0, 0);
}

__global__ __launch_bounds__(512, 2) void mfma_dual8(
    const __hip_bfloat16* __restrict__ A, const __hip_bfloat16* __restrict__ Alo,
    const __hip_bfloat16* __restrict__ Bt, const __hip_bfloat16* __restrict__ Btlo,
    const float* __restrict__ bias, float* __restrict__ C,
    int K, int ldc, int NT) {
  __shared__ __hip_bfloat16 sm[2][4][256 * 32];  // 128 KiB, [buf][Ah,Bh,Al,Bl]
  const int tid = threadIdx.x;
  const int w = tid >> 6, lane = tid & 63;
  const int wm = w >> 2, wn = w & 3;
  // T1: XCD-aware block swizzle (nwg = 256, % 8 == 0)
  const int nwg = gridDim.x * gridDim.y;
  const int bid = blockIdx.y * gridDim.x + blockIdx.x;
  const int swz = (bid & 7) * (nwg >> 3) + (bid >> 3);
  const int ty = swz % gridDim.y, tx = swz / gridDim.y;  // col-major: B-panel/XCD
  const long row0 = (long)ty * 256, col0 = (long)tx * 256;
  const int urow = tid >> 2;
  const int qg = (tid & 3) ^ ((tid >> 3) & 3);
  const long ga0 = (row0 + urow) * (long)K + qg * 8, ga1 = ga0 + 128L * K;
  const long gb0 = (col0 + urow) * (long)K + qg * 8, gb1 = gb0 + 128L * K;
  const int fr = lane & 15, q = lane >> 4;
  const int ro = fr * 32 + ((q ^ ((fr >> 1) & 3)) << 3);
  const int arow = wm * 128, brow = wn * 64;
  const int lw = w * 512;  // wave-uniform LDS chunk within a unit-half
  f32x4 acc[8][4] = {};

  auto stage = [&](int b, long k) {
    gload_lds16(A + ga0 + k, &sm[b][0][lw]);
    gload_lds16(A + ga1 + k, &sm[b][0][4096 + lw]);
    gload_lds16(Bt + gb0 + k, &sm[b][1][lw]);
    gload_lds16(Bt + gb1 + k, &sm[b][1][4096 + lw]);
    gload_lds16(Alo + ga0 + k, &sm[b][2][lw]);
    gload_lds16(Alo + ga1 + k, &sm[b][2][4096 + lw]);
    gload_lds16(Btlo + gb0 + k, &sm[b][3][lw]);
    gload_lds16(Btlo + gb1 + k, &sm[b][3][4096 + lw]);
  };

  // prologue: stage K-tile 0 into buf 0
  stage(0, 0);
  asm volatile("s_waitcnt vmcnt(0)" ::: "memory");
  __builtin_amdgcn_s_barrier();

  for (int t = 0; t < NT; ++t) {
    const int cur = t & 1, nxt = cur ^ 1;
    if (t + 1 < NT) stage(nxt, (long)(t + 1) << 5);
    const __hip_bfloat16* sA = sm[cur][0];
    const __hip_bfloat16* sB = sm[cur][1];
    const __hip_bfloat16* sAl = sm[cur][2];
    const __hip_bfloat16* sBl = sm[cur][3];
    bf16x8 bh[4], bl[4], a0[4], a1[4];
    rd4(bh, sB, brow, ro);
    rd4(bl, sBl, brow, ro);
    rd4(a0, sA, arow, ro);
    rd4(a1, sA, arow + 64, ro);
    __builtin_amdgcn_s_setprio(1);
    mm16(acc, 0, a0, bh);
    mm16(acc, 1, a1, bh);
    mm16(acc, 0, a0, bl);
    mm16(acc, 1, a1, bl);
    __builtin_amdgcn_s_setprio(0);
    rd4(a0, sAl, arow, ro);
    rd4(a1, sAl, arow + 64, ro);
    __builtin_amdgcn_s_setprio(1);
    mm16(acc, 0, a0, bh);
    mm16(acc, 1, a1, bh);
    __builtin_amdgcn_s_setprio(0);
    asm volatile("s_waitcnt vmcnt(0)" ::: "memory");
    __builtin_amdgcn_s_barrier();
  }

  // ---- epilogue: full-line stores via LDS slab transpose (write-allocate fix)
  float* ep = (float*)&sm[0][0][0];
  const int EPLD = 260;
  float bvj[4];
#pragma unroll
  for (int j = 0; j < 4; ++j) bvj[j] = bias[col0 + wn * 64 + j * 16 + fr];
  const int band = tid >> 8, tl = tid & 255;
#pragma unroll
  for (int i = 0; i < 8; ++i) {
    __builtin_amdgcn_s_barrier();  // LDS free (K-loop or previous slab done)
#pragma unroll
    for (int j = 0; j < 4; ++j) {
      int colt = wn * 64 + j * 16 + fr;
#pragma unroll
      for (int r = 0; r < 4; ++r)
        ep[(wm * 16 + q * 4 + r) * EPLD + colt] = acc[i][j][r] + bvj[j];
    }
    __builtin_amdgcn_s_barrier();
#pragma unroll
    for (int s = 0; s < 4; ++s) {
      int idx = s * 256 + tl;
      int rw = idx >> 6, c4 = idx & 63;
      float4 v = *(const float4*)&ep[(band * 16 + rw) * EPLD + c4 * 4];
      long grow = row0 + band * 128 + i * 16 + rw;
      *(float4*)&C[grow * (long)ldc + col0 + c4 * 4] = v;
    }
  }
}

// ---------------- edge kernels: CSR build + gathers ----------------------------
__global__ __launch_bounds__(256) void count_edges(
    const int* __restrict__ ei, const int* __restrict__ et, float* __restrict__ cnt) {
  int e = blockIdx.x * 256 + threadIdx.x;
  if (e < EE) atomicAdd(&cnt[ei[EE + e] * RR + et[e]], 1.0f);
}

__global__ __launch_bounds__(256) void scan_rowptr(
    const float* __restrict__ cntf, int* __restrict__ rowptr, int* __restrict__ fill) {
  __shared__ int part[256];
  int tid = threadIdx.x;
  int base = tid * 32;
  int local[32];
  int s = 0;
  for (int i = 0; i < 32; ++i) {
    local[i] = s;
    const float* c = &cntf[(base + i) * RR];
    int d = 0;
#pragma unroll
    for (int r = 0; r < RR; ++r) d += (int)c[r];
    s += d;
  }
  part[tid] = s;
  __syncthreads();
  for (int off = 1; off < 256; off <<= 1) {
    int v = (tid >= off) ? part[tid - off] : 0;
    __syncthreads();
    part[tid] += v;
    __syncthreads();
  }
  int prev = (tid == 0) ? 0 : part[tid - 1];
  for (int i = 0; i < 32; ++i) rowptr[base + i] = prev + local[i];
  if (tid == 255) rowptr[8192] = part[255];
  for (int i = tid; i < 8192; i += 256) fill[i] = 0;
}

__global__ __launch_bounds__(256) void edge_fill(
    const int* __restrict__ ei, const int* __restrict__ et,
    const int* __restrict__ rowptr, int* __restrict__ fill, int* __restrict__ eidx) {
  int e = blockIdx.x * 256 + threadIdx.x;
  if (e < EE) {
    int dst = ei[EE + e];
    int pos = rowptr[dst] + atomicAdd(&fill[dst], 1);
    eidx[pos] = ei[e] | (et[e] << 16);
  }
}

// out1 += mean-agg; emit split into a2o1 cols 256:512. Wave-split float4
// gather: wave w owns edges i%4==w, lane l covers cols 4l..4l+3.
__global__ __launch_bounds__(256) void rgcn_gather(
    const int* __restrict__ rowptr, const int* __restrict__ eidx,
    const float* __restrict__ cntf, const float* __restrict__ xw,
    float* __restrict__ out1, __hip_bfloat16* __restrict__ a2o1_hi,
    __hip_bfloat16* __restrict__ a2o1_lo) {
  const int dst = blockIdx.x;
  const int tid = threadIdx.x;
  const int w = tid >> 6, lane = tid & 63;
  const int c4 = lane * 4;
  __shared__ float inv[RR];
  __shared__ int se[256];
  __shared__ float part[3][256];
  if (tid < RR) inv[tid] = 1.0f / fmaxf(cntf[dst * RR + tid], 1.0f);
  const int beg = rowptr[dst], end = rowptr[dst + 1];
  float4 a = make_float4(0.f, 0.f, 0.f, 0.f);
  for (int c0 = beg; c0 < end; c0 += 256) {
    int n = min(256, end - c0);
    __syncthreads();
    if (tid < n) se[tid] = eidx[c0 + tid];
    __syncthreads();
    int i = w;
    for (; i + 4 < n; i += 8) {
      int p0 = se[i], p1 = se[i + 4];
      float4 v0 = *(const float4*)&xw[((long)(p0 & 0xFFFF) << 12) + ((p0 >> 16) << 8) + c4];
      float4 v1 = *(const float4*)&xw[((long)(p1 & 0xFFFF) << 12) + ((p1 >> 16) << 8) + c4];
      float s0 = inv[p0 >> 16], s1 = inv[p1 >> 16];
      a.x += v0.x * s0 + v1.x * s1;
      a.y += v0.y * s0 + v1.y * s1;
      a.z += v0.z * s0 + v1.z * s1;
      a.w += v0.w * s0 + v1.w * s1;
    }
    for (; i < n; i += 4) {
      int p0 = se[i];
      float4 v0 = *(const float4*)&xw[((long)(p0 & 0xFFFF) << 12) + ((p0 >> 16) << 8) + c4];
      float s0 = inv[p0 >> 16];
      a.x += v0.x * s0;
      a.y += v0.y * s0;
      a.z += v0.z * s0;
      a.w += v0.w * s0;
    }
  }
  __syncthreads();
  if (w) *(float4*)&part[w - 1][c4] = a;
  __syncthreads();
  if (w == 0) {
    float4 p0 = *(const float4*)&part[0][c4];
    float4 p1 = *(const float4*)&part[1][c4];
    float4 p2 = *(const float4*)&part[2][c4];
    long ob = ((long)dst << 8) + c4;
    float4 o = *(const float4*)&out1[ob];
    float t0 = o.x + a.x + p0.x + p1.x + p2.x;
    float t1 = o.y + a.y + p0.y + p1.y + p2.y;
    float t2 = o.z + a.z + p0.z + p1.z + p2.z;
    float t3 = o.w + a.w + p0.w + p1.w + p2.w;
    *(float4*)&out1[ob] = make_float4(t0, t1, t2, t3);
    __hip_bfloat16 h0 = __float2bfloat16(t0), h1 = __float2bfloat16(t1),
                   h2 = __float2bfloat16(t2), h3 = __float2bfloat16(t3);
    ushort4 hv = {*(unsigned short*)&h0, *(unsigned short*)&h1,
                  *(unsigned short*)&h2, *(unsigned short*)&h3};
    __hip_bfloat16 l0 = __float2bfloat16(t0 - __bfloat162float(h0)),
                   l1 = __float2bfloat16(t1 - __bfloat162float(h1)),
                   l2 = __float2bfloat16(t2 - __bfloat162float(h2)),
                   l3 = __float2bfloat16(t3 - __bfloat162float(h3));
    ushort4 lv = {*(unsigned short*)&l0, *(unsigned short*)&l1,
                  *(unsigned short*)&l2, *(unsigned short*)&l3};
    long d = (long)dst * 512 + 256 + c4;
    *(ushort4*)(a2o1_hi + d) = hv;
    *(ushort4*)(a2o1_lo + d) = lv;
  }
}

// a2o1 cols 0:256 = sum_{src->dst} out1[src] (wave-split float4, same scheme)
__global__ __launch_bounds__(256) void graphconv_gather(
    const int* __restrict__ rowptr, const int* __restrict__ eidx,
    const float* __restrict__ out1, __hip_bfloat16* __restrict__ a2o1_hi,
    __hip_bfloat16* __restrict__ a2o1_lo) {
  const int dst = blockIdx.x;
  const int tid = threadIdx.x;
  const int w = tid >> 6, lane = tid & 63;
  const int c4 = lane * 4;
  __shared__ int se[256];
  __shared__ float part[3][256];
  const int beg = rowptr[dst], end = rowptr[dst + 1];
  float4 a = make_float4(0.f, 0.f, 0.f, 0.f);
  for (int c0 = beg; c0 < end; c0 += 256) {
    int n = min(256, end - c0);
    __syncthreads();
    if (tid < n) se[tid] = eidx[c0 + tid];
    __syncthreads();
    int i = w;
    for (; i + 4 < n; i += 8) {
      float4 v0 = *(const float4*)&out1[((long)(se[i] & 0xFFFF) << 8) + c4];
      float4 v1 = *(const float4*)&out1[((long)(se[i + 4] & 0xFFFF) << 8) + c4];
      a.x += v0.x + v1.x;
      a.y += v0.y + v1.y;
      a.z += v0.z + v1.z;
      a.w += v0.w + v1.w;
    }
    for (; i < n; i += 4) {
      float4 v0 = *(const float4*)&out1[((long)(se[i] & 0xFFFF) << 8) + c4];
      a.x += v0.x;
      a.y += v0.y;
      a.z += v0.z;
      a.w += v0.w;
    }
  }
  __syncthreads();
  if (w) *(float4*)&part[w - 1][c4] = a;
  __syncthreads();
  if (w == 0) {
    float4 p0 = *(const float4*)&part[0][c4];
    float4 p1 = *(const float4*)&part[1][c4];
    float4 p2 = *(const float4*)&part[2][c4];
    float t0 = a.x + p0.x + p1.x + p2.x;
    float t1 = a.y + p0.y + p1.y + p2.y;
    float t2 = a.z + p0.z + p1.z + p2.z;
    float t3 = a.w + p0.w + p1.w + p2.w;
    __hip_bfloat16 h0 = __float2bfloat16(t0), h1 = __float2bfloat16(t1),
                   h2 = __float2bfloat16(t2), h3 = __float2bfloat16(t3);
    ushort4 hv = {*(unsigned short*)&h0, *(unsigned short*)&h1,
                  *(unsigned short*)&h2, *(unsigned short*)&h3};
    __hip_bfloat16 l0 = __float2bfloat16(t0 - __bfloat162float(h0)),
                   l1 = __float2bfloat16(t1 - __bfloat162float(h1)),
                   l2 = __float2bfloat16(t2 - __bfloat162float(h2)),
                   l3 = __float2bfloat16(t3 - __bfloat162float(h3));
    ushort4 lv = {*(unsigned short*)&l0, *(unsigned short*)&l1,
                  *(unsigned short*)&l2, *(unsigned short*)&l3};
    long d = (long)dst * 512 + c4;
    *(ushort4*)(a2o1_hi + d) = hv;
    *(ushort4*)(a2o1_lo + d) = lv;
  }
}

// ---------------- softmax over last dim (256), bf16 weights out ---------------
__global__ __launch_bounds__(256) void softmax256(const float* __restrict__ S,
                                                  __hip_bfloat16* __restrict__ Ab) {
  __shared__ float red[256];
  long row = blockIdx.x;
  const float* p = S + row * 256;
  int t = threadIdx.x;
  float v = p[t];
  red[t] = v;
  __syncthreads();
  for (int s = 128; s > 0; s >>= 1) {
    if (t < s) red[t] = fmaxf(red[t], red[t + s]);
    __syncthreads();
  }
  float m = red[0];
  __syncthreads();
  float e = __expf(v - m);
  red[t] = e;
  __syncthreads();
  for (int s = 128; s > 0; s >>= 1) {
    if (t < s) red[t] += red[t + s];
    __syncthreads();
  }
  Ab[row * 256 + t] = __float2bfloat16(e / red[0]);
}

// ---------------- logits + log_softmax over batch axis (faithful dim=1) -------
__global__ __launch_bounds__(256) void logits_lsm(
    const float* __restrict__ hidden, const float* __restrict__ w_fc,
    const float* __restrict__ b_fc, void* __restrict__ out_v,
    const int* __restrict__ flag) {
  __shared__ float wf[256 * 7];
  __shared__ float lg[224];
  __shared__ float corr[7];
  int t = blockIdx.x;
  int tid = threadIdx.x;
  for (int i = tid; i < 256 * 7; i += 256) wf[i] = w_fc[i];
  __syncthreads();
  if (tid < 224) {
    int b = tid / 7, c = tid % 7;
    const float* hr = hidden + ((long)((b << 8) + t) << 8);
    float s = b_fc[c];
    for (int k = 0; k < 256; ++k) s += hr[k] * wf[k * 7 + c];
    lg[tid] = s;
  }
  __syncthreads();
  if (tid < 7) {
    float m = -1e30f;
    for (int b = 0; b < BB; ++b) m = fmaxf(m, lg[b * 7 + tid]);
    float sum = 0.f;
    for (int b = 0; b < BB; ++b) sum += __expf(lg[b * 7 + tid] - m);
    corr[tid] = m + logf(sum);
  }
  __syncthreads();
  if (tid < 224) {
    float v = lg[tid] - corr[tid % 7];
    if (flag[0]) ((float*)out_v)[t * 224 + tid] = v;
    else ((__hip_bfloat16*)out_v)[t * 224 + tid] = __float2bfloat16(v);
  }
}

extern "C" void kernel_launch(void* const* d_in, const int* in_sizes, int n_in,
                              void* d_out, int out_size, void* d_ws, size_t ws_size,
                              hipStream_t stream) {
  const int* ei = (const int*)d_in[1];
  const int* et = (const int*)d_in[3];

  float* ws = (float*)d_ws;
  int* flag = (int*)d_ws;
  float* p = ws + 16;
  auto alloc = [&](long nf) { float* r = p; p += nf; return r; };
  float* w_fc_f = alloc(1792);
  float* b_rel_f = alloc(256);
  float* biasx = alloc(4352);                                    // [0..4095]=0, tail=bias1
  float* battx = alloc(1024);                                    // [0..767]=b_att, rest 0
  float* b_lin_f = alloc(256);
  float* b_fc_f = alloc(16);
  __hip_bfloat16* x_hi = (__hip_bfloat16*)alloc(2097152);        // [8192][512]
  __hip_bfloat16* x_lo = (__hip_bfloat16*)alloc(2097152);
  __hip_bfloat16* wae_hi = (__hip_bfloat16*)alloc(393216);       // [1024][768] = [w_att|w_lin]^T
  __hip_bfloat16* wae_lo = (__hip_bfloat16*)alloc(393216);
  __hip_bfloat16* wrr_hi = (__hip_bfloat16*)alloc(65536);        // [256][512] = [w_rel;w_root]^T
  __hip_bfloat16* wrr_lo = (__hip_bfloat16*)alloc(65536);
  __hip_bfloat16* wtc_hi = (__hip_bfloat16*)alloc(1114112);      // [4352][512]
  __hip_bfloat16* wtc_lo = (__hip_bfloat16*)alloc(1114112);
  float* basis_f = alloc(3932160);
  float* comp_f = alloc(512);
  float* xw = alloc(33554432);   // fp32 [8192][4096]; overlays below
  float* cnt = alloc(131072);
  float* out1 = alloc(2097152);
  __hip_bfloat16* a2o1_hi = (__hip_bfloat16*)alloc(2097152);     // [8192][512]
  __hip_bfloat16* a2o1_lo = (__hip_bfloat16*)alloc(2097152);
  float* hidden = alloc(2097152);
  int* rowptr = (int*)alloc(8208);
  int* fillc = (int*)alloc(8192);
  int* eidx = (int*)alloc(262144);
  // wt_nat overlays head of xw (consumed by wt_transpose before xw is written)
  float* wt_nat = xw;                                            // [16][512][256]
  // phase B overlays the (consumed) xw region
  float* em = xw;
  __hip_bfloat16* emwT_hi = (__hip_bfloat16*)(em + 2097152);     // [32][256][256]
  __hip_bfloat16* emwT_lo = (__hip_bfloat16*)(em + 3145728);
  __hip_bfloat16* em_hi = (__hip_bfloat16*)(em + 6291456);       // [8192][768]
  __hip_bfloat16* em_lo = (__hip_bfloat16*)(em + 9437184);
  __hip_bfloat16* X_hi = (__hip_bfloat16*)(em + 12582912);
  __hip_bfloat16* X_lo = (__hip_bfloat16*)(em + 15728640);
  float* scores = em + 18874368;                                 // 2,097,152 f
  __hip_bfloat16* a_b16 = (__hip_bfloat16*)(em + 20971520);      // 1,048,576 f

  // 0. dtype detect + one unified prep launch
  detect_dtype<<<1, 256, 0, stream>>>((const unsigned short*)d_in[0], flag);
  PTable T{};
  long tot = 0;
  int ns = 0;
  auto segL = [&](const void* s, float* d, __hip_bfloat16* hi, __hip_bfloat16* lo,
                  __hip_bfloat16* hi2, __hip_bfloat16* lo2, long n, int z) {
    T.seg[ns] = PSeg{s, d, hi, lo, hi2, lo2, n, 0, 0, 0, 0, 0, z};
    ns++; tot += n;
  };
  auto segT = [&](const void* s, __hip_bfloat16* hi, __hip_bfloat16* lo,
                  int R, int C, int ld, int off) {
    T.seg[ns] = PSeg{s, nullptr, hi, lo, nullptr, nullptr, (long)R * C, R, C, ld, off, 1, 0};
    ns++; tot += (long)R * C;
  };
  segL(d_in[0], nullptr, x_hi, x_lo, nullptr, nullptr, NN * FF, 0);
  segL(d_in[8], basis_f, nullptr, nullptr, nullptr, nullptr, NBASE * FF * HH, 0);
  segL(d_in[9], comp_f, nullptr, nullptr, nullptr, nullptr, RR * NBASE, 0);
  segL(d_in[13], b_rel_f, nullptr, nullptr, nullptr, nullptr, HH, 0);
  segL(d_in[16], battx, nullptr, nullptr, nullptr, nullptr, DD, 0);
  segL(nullptr, battx + DD, nullptr, nullptr, nullptr, nullptr, 256, 1);
  segL(d_in[18], b_lin_f, nullptr, nullptr, nullptr, nullptr, HH, 0);
  segL(d_in[19], w_fc_f, nullptr, nullptr, nullptr, nullptr, HH * CC, 0);
  segL(d_in[20], b_fc_f, nullptr, nullptr, nullptr, nullptr, CC, 0);
  segL(nullptr, biasx, nullptr, nullptr, nullptr, nullptr, 4096, 1);
  segL(d_in[11], biasx + 4096, nullptr, nullptr, nullptr, nullptr, HH, 0);
  segT(d_in[15], wae_hi, wae_lo, DD, DD, DD, 0);                 // w_att^T -> rows 0:768
  segT(d_in[17], wae_hi + 768 * 768, wae_lo + 768 * 768, DD, HH, DD, 0);  // w_lin^T -> rows 768:1024
  segT(d_in[10], wtc_hi + 4096 * 512, wtc_lo + 4096 * 512, FF, HH, FF, 0);  // root1^T
  segT(d_in[12], wrr_hi, wrr_lo, HH, HH, 512, 0);                // w_rel^T
  segT(d_in[14], wrr_hi, wrr_lo, HH, HH, 512, 256);              // w_root^T
  T.count = ns;
  T.total = tot;
  prep_all<<<4096, 256, 0, stream>>>(T, flag);

  // 1. Wt: coalesced GEMM into natural layout, then LDS-tiled transpose + split
  wt_gemm<<<131072 / 256, 256, 0, stream>>>(basis_f, comp_f, wt_nat);
  wt_transpose<<<dim3(8, 16, 16), 256, 0, stream>>>(wt_nat, wtc_hi, wtc_lo);
  // 2. xw = x @ W (cols 0:4096) as two half-N launches, 256 blocks each
  mfma_dual8<<<dim3(8, 32), 512, 0, stream>>>(
      x_hi, x_lo, wtc_hi, wtc_lo, biasx, xw, FF, 4096, FF / 32);
  mfma_dual8<<<dim3(8, 32), 512, 0, stream>>>(
      x_hi, x_lo, wtc_hi + 2048 * 512, wtc_lo + 2048 * 512, biasx + 2048,
      xw + 2048, FF, 4096, FF / 32);
  // 2b. out1 = x @ root1 + bias1 — 64x64 tiles: grid (4,128) = 512 blocks
  //     (was (2,64)=128 blocks = 0.5 block/CU latency-bound)
  mfma_b64<<<dim3(4, 128, 1), 256, 0, stream>>>(
      x_hi, x_lo, wtc_hi + 4096 * 512, wtc_lo + 4096 * 512, biasx + 4096,
      out1, FF, HH, 0, 0, 0, FLAG_BIAS);
  // 3. CSR build
  hipMemsetAsync(cnt, 0, 131072 * sizeof(float), stream);
  count_edges<<<EE / 256, 256, 0, stream>>>(ei, et, cnt);
  scan_rowptr<<<1, 256, 0, stream>>>(cnt, rowptr, fillc);
  edge_fill<<<EE / 256, 256, 0, stream>>>(ei, et, rowptr, fillc, eidx);
  // 4/5. aggregations (gather); emit [agg2|out1] hi/lo as out2-GEMM A operand
  rgcn_gather<<<NN, 256, 0, stream>>>(rowptr, eidx, cnt, xw, out1, a2o1_hi, a2o1_lo);
  graphconv_gather<<<NN, 256, 0, stream>>>(rowptr, eidx, out1, a2o1_hi, a2o1_lo);
  // 6. em cols 0:512 = x (split, from x_hi/x_lo after xw is dead)
  extern __global__ void copy_xsplit_k(const __hip_bfloat16*, const __hip_bfloat16*,
                                       __hip_bfloat16*, __hip_bfloat16*);
  copy_xsplit_k<<<(NN * FF) / 256, 256, 0, stream>>>(x_hi, x_lo, em_hi, em_lo);
  // 6b. out2 -> em cols 512:768 via split-MFMA (bf16-split epilogue)
  mfma_dual<<<dim3(2, 64, 1), 256, 0, stream>>>(
      a2o1_hi, a2o1_lo, wrr_hi, wrr_lo, b_rel_f, nullptr, nullptr,
      em_hi + 512, em_lo + 512, nullptr, nullptr, 512, DD, 0, 0, 0,
      FLAG_BIAS | FLAG_SPLITOUT);
  // 7. [X | emwT] = em @ [w_att | w_lin] (+b_att|0); cols>=768 -> transposed split
  //    2-phase mfma_dual @ 3 blocks/CU (r9: 1-block/CU 256x128 variant regressed).
  mfma_dual<<<dim3(8, 64, 1), 256, 0, stream>>>(
      em_hi, em_lo, wae_hi, wae_lo, battx, nullptr, nullptr, X_hi, X_lo,
      emwT_hi, emwT_lo, DD, DD, 0, 0, 0, FLAG_BIAS | FLAG_SPLITOUT | FLAG_TAIL2);
  // 8. scores = tanh(X_b . em_b^T) — 64x64 tiles: grid (4,4,32) = 512 blocks
  //    (was (2,2,32)=128 blocks: 104.7us, Occ 5.4%, MfmaUtil 3.4% in r11 profile)
  mfma_b64<<<dim3(4, 4, BB), 256, 0, stream>>>(
      X_hi, X_lo, em_hi, em_lo, nullptr, scores, DD, LL,
      (long)LL * DD, (long)LL * DD, (long)LL * LL, FLAG_TANH);
  // 9. softmax over s -> bf16 attention weights
  softmax256<<<BB * LL, 256, 0, stream>>>(scores, a_b16);
  // 10. hidden = relu(a @ emwT + b_lin) — 64x64 tiles: grid (4,4,32)
  mfma_b64<<<dim3(4, 4, BB), 256, 0, stream>>>(
      a_b16, nullptr, emwT_hi, emwT_lo, b_lin_f, hidden, LL, HH,
      (long)LL * LL, (long)LL * HH, (long)LL * HH, FLAG_BIAS | FLAG_RELU);
  // 11. logits + log_softmax over batch axis
  logits_lsm<<<LL, 256, 0, stream>>>(hidden, w_fc_f, b_fc_f, d_out, flag);
}

// copy x_hi/x_lo [8192][512] into em_hi/lo [8192][768] cols 0:512
__global__ __launch_bounds__(256) void copy_xsplit_k(
    const __hip_bfloat16* __restrict__ xh, const __hip_bfloat16* __restrict__ xl,
    __hip_bfloat16* __restrict__ eh, __hip_bfloat16* __restrict__ el) {
  int idx = blockIdx.x * 256 + threadIdx.x;  // 8192*512
  int n = idx >> 9, f = idx & 511;
  long d = (long)n * DD + f;
  eh[d] = xh[idx];
  el[d] = xl[idx];
}